// Round 1
// baseline (2086.318 us; speedup 1.0000x reference)
//
#include <hip/hip_runtime.h>
#include <math.h>

#define N_NODES 20000
#define N_EDGES 160000
#define DIM_IN  128
#define HIDDEN  96
#define NH      6
#define HD      576      // NH*HIDDEN
#define LDQ     1824     // 3*HD + HIDDEN  (Q | K | V | S) row stride
#define NGRAPH  512
#define NCLS    128

// ---------------------------------------------------------------------------
// Generic fp32 GEMM: C[M, ncols](+col_off into ldc-stride rows) = A[M,K] @ W[K,ncols] + bias
// 64x64 tile, 256 threads, each thread 4x4. LDS stride 68 to dodge bank conflicts.
// ---------------------------------------------------------------------------
__global__ __launch_bounds__(256) void gemm_bias(
    const float* __restrict__ A, int M, int K,
    const float* __restrict__ W, const float* __restrict__ bias,
    float* __restrict__ C, int ldc, int ncols, int col_off)
{
    __shared__ float As[128 * 68];
    __shared__ float Bs[128 * 68];
    int t  = threadIdx.x;
    int tx = t & 15, ty = t >> 4;
    int m0 = blockIdx.y * 64;
    int n0 = blockIdx.x * 64;
    int K4 = K >> 2;

    // A tile, stored transposed: As[k*68 + r]
    for (int i = t; i < 64 * K4; i += 256) {
        int r = i / K4, k4 = i - r * K4;
        int row = m0 + r;
        float4 v = make_float4(0.f, 0.f, 0.f, 0.f);
        if (row < M) v = *(const float4*)(A + (size_t)row * K + k4 * 4);
        As[(4 * k4 + 0) * 68 + r] = v.x;
        As[(4 * k4 + 1) * 68 + r] = v.y;
        As[(4 * k4 + 2) * 68 + r] = v.z;
        As[(4 * k4 + 3) * 68 + r] = v.w;
    }
    // B tile: Bs[k*68 + c]
    for (int i = t; i < K * 16; i += 256) {
        int k = i >> 4, c4 = i & 15;
        int col = n0 + c4 * 4;
        float4 v = make_float4(0.f, 0.f, 0.f, 0.f);
        if (col < ncols) v = *(const float4*)(W + (size_t)k * ncols + col);
        *(float4*)(&Bs[k * 68 + c4 * 4]) = v;
    }
    __syncthreads();

    float acc[4][4] = {};
    #pragma unroll 4
    for (int k = 0; k < K; k++) {
        float4 a = *(const float4*)(&As[k * 68 + ty * 4]);
        float4 b = *(const float4*)(&Bs[k * 68 + tx * 4]);
        float av[4] = {a.x, a.y, a.z, a.w};
        float bv[4] = {b.x, b.y, b.z, b.w};
        #pragma unroll
        for (int i = 0; i < 4; i++)
            #pragma unroll
            for (int j = 0; j < 4; j++)
                acc[i][j] += av[i] * bv[j];
    }

    int c0 = n0 + tx * 4;
    if (c0 < ncols) {
        float4 bb = *(const float4*)(bias + c0);
        #pragma unroll
        for (int i = 0; i < 4; i++) {
            int row = m0 + ty * 4 + i;
            if (row < M) {
                float4 o;
                o.x = acc[i][0] + bb.x;
                o.y = acc[i][1] + bb.y;
                o.z = acc[i][2] + bb.z;
                o.w = acc[i][3] + bb.w;
                *(float4*)(C + (size_t)row * ldc + col_off + c0) = o;
            }
        }
    }
}

// ---------------------------------------------------------------------------
// CSR construction by destination node
// ---------------------------------------------------------------------------
__global__ void k_deg(const int* __restrict__ edst, int* __restrict__ deg)
{
    int e = blockIdx.x * blockDim.x + threadIdx.x;
    if (e < N_EDGES) atomicAdd(&deg[edst[e]], 1);
}

__global__ __launch_bounds__(1024) void k_scan(const int* __restrict__ deg,
                                               int* __restrict__ row_ptr,
                                               int* __restrict__ cursor)
{
    __shared__ int part[1024];
    int t = threadIdx.x;
    const int chunk = (N_NODES + 1023) / 1024;  // 20
    int b = t * chunk;
    int s = 0;
    for (int i = 0; i < chunk; i++)
        if (b + i < N_NODES) s += deg[b + i];
    part[t] = s;
    __syncthreads();
    for (int o = 1; o < 1024; o <<= 1) {
        int v = (t >= o) ? part[t - o] : 0;
        __syncthreads();
        part[t] += v;
        __syncthreads();
    }
    int run = part[t] - s;  // exclusive prefix
    for (int i = 0; i < chunk; i++) {
        if (b + i < N_NODES) {
            row_ptr[b + i] = run;
            cursor[b + i]  = run;
            run += deg[b + i];
        }
    }
    if (t == 1023) row_ptr[N_NODES] = part[1023];
}

__global__ void k_scatter(const int* __restrict__ edst, int* __restrict__ cursor,
                          int* __restrict__ eidx)
{
    int e = blockIdx.x * blockDim.x + threadIdx.x;
    if (e < N_EDGES) {
        int pos = atomicAdd(&cursor[edst[e]], 1);
        eidx[pos] = e;
    }
}

// ---------------------------------------------------------------------------
// Edge attention logits: alpha[e][h] = dot96(Q[dst]+h*96, K[src]+h*96)/sqrt(96)
// One 32-lane group per (edge, head); coalesced 96-float row reads.
// ---------------------------------------------------------------------------
__global__ __launch_bounds__(256) void edge_alpha(
    const float* __restrict__ qkv, const int* __restrict__ esrc,
    const int* __restrict__ edst, float* __restrict__ alpha)
{
    int gid  = blockIdx.x * 8 + (threadIdx.x >> 5);
    int lane = threadIdx.x & 31;
    if (gid >= N_EDGES * NH) return;
    int e = gid / NH;
    int h = gid - e * NH;
    const float* q  = qkv + (size_t)edst[e] * LDQ + h * HIDDEN;
    const float* kk = qkv + (size_t)esrc[e] * LDQ + HD + h * HIDDEN;
    float p = q[lane] * kk[lane] + q[lane + 32] * kk[lane + 32]
            + q[lane + 64] * kk[lane + 64];
    #pragma unroll
    for (int o = 16; o; o >>= 1) p += __shfl_xor(p, o, 32);
    if (lane == 0) alpha[e * NH + h] = p * 0.10206207261596577f;  // 1/sqrt(96)
}

// ---------------------------------------------------------------------------
// Per-destination-node segment softmax + weighted V aggregation + head-mean
// + skip + ReLU. One block (192 threads, 3 waves) per node; no atomics.
// ---------------------------------------------------------------------------
__global__ __launch_bounds__(192) void node_aggregate(
    const float* __restrict__ qkv, const float* __restrict__ alpha,
    const int* __restrict__ row_ptr, const int* __restrict__ eidx,
    const int* __restrict__ esrc, float* __restrict__ hout)
{
    int n = blockIdx.x;
    int t = threadIdx.x;
    __shared__ float sm[NH], sinv[NH];
    __shared__ float arr[HD];
    int beg = row_ptr[n], end = row_ptr[n + 1];

    if (t < NH && beg < end) {
        float m = -1e30f;
        for (int i = beg; i < end; i++) m = fmaxf(m, alpha[eidx[i] * NH + t]);
        float s = 0.f;
        for (int i = beg; i < end; i++) s += __expf(alpha[eidx[i] * NH + t] - m);
        sm[t]   = m;
        sinv[t] = 1.0f / s;
    }
    __syncthreads();

    int d0 = t, d1 = t + 192, d2 = t + 384;
    int h0 = d0 / HIDDEN, h1 = d1 / HIDDEN, h2 = d2 / HIDDEN;
    float a0 = 0.f, a1 = 0.f, a2 = 0.f;
    for (int i = beg; i < end; i++) {
        int e  = eidx[i];
        int sv = esrc[e];
        const float* v  = qkv + (size_t)sv * LDQ + 2 * HD;
        const float* al = alpha + (size_t)e * NH;
        float w0 = __expf(al[h0] - sm[h0]) * sinv[h0];
        float w1 = __expf(al[h1] - sm[h1]) * sinv[h1];
        float w2 = __expf(al[h2] - sm[h2]) * sinv[h2];
        a0 += w0 * v[d0];
        a1 += w1 * v[d1];
        a2 += w2 * v[d2];
    }
    arr[d0] = a0; arr[d1] = a1; arr[d2] = a2;
    __syncthreads();

    if (t < HIDDEN) {
        float s = (arr[t] + arr[HIDDEN + t] + arr[2 * HIDDEN + t] +
                   arr[3 * HIDDEN + t] + arr[4 * HIDDEN + t] + arr[5 * HIDDEN + t])
                  * (1.0f / 6.0f);
        s += qkv[(size_t)n * LDQ + 3 * HD + t];  // skip connection S
        hout[n * HIDDEN + t] = fmaxf(s, 0.0f);
    }
}

// ---------------------------------------------------------------------------
// Global mean pool (sums + counts via atomics)
// ---------------------------------------------------------------------------
__global__ void k_pool(const float* __restrict__ h, const int* __restrict__ batch,
                       float* __restrict__ gsum, int* __restrict__ gcnt)
{
    int i = blockIdx.x * blockDim.x + threadIdx.x;
    if (i >= N_NODES * HIDDEN) return;
    int n = i / HIDDEN, d = i - n * HIDDEN;
    int b = batch[n];
    atomicAdd(&gsum[b * HIDDEN + d], h[i]);
    if (d == 0) atomicAdd(&gcnt[b], 1);
}

// ---------------------------------------------------------------------------
// Head: mean -> fc1+relu -> fc2+relu -> ArcFace cosine logits * 30
// One block of 128 threads per graph.
// ---------------------------------------------------------------------------
__global__ __launch_bounds__(128) void k_head(
    const float* __restrict__ gsum, const int* __restrict__ gcnt,
    const float* __restrict__ fc1w, const float* __restrict__ fc1b,
    const float* __restrict__ fc2w, const float* __restrict__ fc2b,
    const float* __restrict__ arcw, float* __restrict__ out)
{
    int g = blockIdx.x, t = threadIdx.x;
    __shared__ float v0[HIDDEN], v1[HIDDEN], v2[HIDDEN];
    __shared__ float gnorm;
    float cnt = fmaxf((float)gcnt[g], 1.0f);
    if (t < HIDDEN) v0[t] = gsum[g * HIDDEN + t] / cnt;
    __syncthreads();
    if (t < HIDDEN) {
        float s = fc1b[t];
        for (int k = 0; k < HIDDEN; k++) s += v0[k] * fc1w[k * HIDDEN + t];
        v1[t] = fmaxf(s, 0.f);
    }
    __syncthreads();
    if (t < HIDDEN) {
        float s = fc2b[t];
        for (int k = 0; k < HIDDEN; k++) s += v1[k] * fc2w[k * HIDDEN + t];
        v2[t] = fmaxf(s, 0.f);
    }
    __syncthreads();
    if (t == 0) {
        float s = 0.f;
        for (int k = 0; k < HIDDEN; k++) s += v2[k] * v2[k];
        gnorm = sqrtf(s) + 1e-12f;
    }
    __syncthreads();
    if (t < NCLS) {
        float dot = 0.f, wn = 0.f;
        const float* wr = arcw + (size_t)t * HIDDEN;
        for (int k = 0; k < HIDDEN; k++) {
            float w = wr[k];
            dot += w * v2[k];
            wn  += w * w;
        }
        out[g * NCLS + t] = 30.0f * dot / (gnorm * (sqrtf(wn) + 1e-12f));
    }
}

// ---------------------------------------------------------------------------
extern "C" void kernel_launch(void* const* d_in, const int* in_sizes, int n_in,
                              void* d_out, int out_size, void* d_ws, size_t ws_size,
                              hipStream_t stream)
{
    (void)in_sizes; (void)n_in; (void)out_size; (void)ws_size;

    const float* x     = (const float*)d_in[0];
    const int*   ei    = (const int*)d_in[1];
    const int*   batch = (const int*)d_in[2];
    const float* Wq1 = (const float*)d_in[3];  const float* bq1 = (const float*)d_in[4];
    const float* Wk1 = (const float*)d_in[5];  const float* bk1 = (const float*)d_in[6];
    const float* Wv1 = (const float*)d_in[7];  const float* bv1 = (const float*)d_in[8];
    const float* Ws1 = (const float*)d_in[9];  const float* bs1 = (const float*)d_in[10];
    const float* Wq_r = (const float*)d_in[11]; const float* bq_r = (const float*)d_in[12];
    const float* Wk_r = (const float*)d_in[13]; const float* bk_r = (const float*)d_in[14];
    const float* Wv_r = (const float*)d_in[15]; const float* bv_r = (const float*)d_in[16];
    const float* Ws_r = (const float*)d_in[17]; const float* bs_r = (const float*)d_in[18];
    const float* fc1w = (const float*)d_in[19]; const float* fc1b = (const float*)d_in[20];
    const float* fc2w = (const float*)d_in[21]; const float* fc2b = (const float*)d_in[22];
    const float* arcw = (const float*)d_in[23];
    float* out = (float*)d_out;

    const int* esrc = ei;            // edge_index[0]
    const int* edst = ei + N_EDGES;  // edge_index[1]

    char* base = (char*)d_ws;
    size_t off = 0;
    auto alloc = [&](size_t bytes) -> void* {
        off = (off + 255) & ~(size_t)255;
        void* p = base + off;
        off += bytes;
        return p;
    };
    float* qkv     = (float*)alloc((size_t)N_NODES * LDQ * 4);   // ~146 MB
    float* alpha   = (float*)alloc((size_t)N_EDGES * NH * 4);
    float* h0      = (float*)alloc((size_t)N_NODES * HIDDEN * 4);
    float* h1      = (float*)alloc((size_t)N_NODES * HIDDEN * 4);
    int*   deg     = (int*)alloc(N_NODES * 4);
    int*   row_ptr = (int*)alloc((N_NODES + 1) * 4);
    int*   cursor  = (int*)alloc(N_NODES * 4);
    int*   eidx    = (int*)alloc(N_EDGES * 4);
    float* gsum    = (float*)alloc(NGRAPH * HIDDEN * 4);
    int*   gcnt    = (int*)alloc(NGRAPH * 4);

    // CSR by destination (graph is identical every call; rebuilt each launch)
    hipMemsetAsync(deg, 0, N_NODES * 4, stream);
    k_deg<<<(N_EDGES + 255) / 256, 256, 0, stream>>>(edst, deg);
    k_scan<<<1, 1024, 0, stream>>>(deg, row_ptr, cursor);
    k_scatter<<<(N_EDGES + 255) / 256, 256, 0, stream>>>(edst, cursor, eidx);

    const float* hin = x;
    float* hcur = h0;
    for (int L = 0; L < 5; L++) {
        int K = (L == 0) ? DIM_IN : HIDDEN;
        const float *Wq, *bq, *Wk, *bk, *Wv, *bv, *Ws, *bs;
        if (L == 0) {
            Wq = Wq1; bq = bq1; Wk = Wk1; bk = bk1;
            Wv = Wv1; bv = bv1; Ws = Ws1; bs = bs1;
        } else {
            int i = L - 1;
            Wq = Wq_r + (size_t)i * HIDDEN * HD; bq = bq_r + (size_t)i * HD;
            Wk = Wk_r + (size_t)i * HIDDEN * HD; bk = bk_r + (size_t)i * HD;
            Wv = Wv_r + (size_t)i * HIDDEN * HD; bv = bv_r + (size_t)i * HD;
            Ws = Ws_r + (size_t)i * HIDDEN * HIDDEN; bs = bs_r + (size_t)i * HIDDEN;
        }
        dim3 gQ(HD / 64, (N_NODES + 63) / 64);
        gemm_bias<<<gQ, 256, 0, stream>>>(hin, N_NODES, K, Wq, bq, qkv, LDQ, HD, 0);
        gemm_bias<<<gQ, 256, 0, stream>>>(hin, N_NODES, K, Wk, bk, qkv, LDQ, HD, HD);
        gemm_bias<<<gQ, 256, 0, stream>>>(hin, N_NODES, K, Wv, bv, qkv, LDQ, HD, 2 * HD);
        dim3 gS((HIDDEN + 63) / 64, (N_NODES + 63) / 64);
        gemm_bias<<<gS, 256, 0, stream>>>(hin, N_NODES, K, Ws, bs, qkv, LDQ, HIDDEN, 3 * HD);

        edge_alpha<<<(N_EDGES * NH) / 8, 256, 0, stream>>>(qkv, esrc, edst, alpha);
        node_aggregate<<<N_NODES, 192, 0, stream>>>(qkv, alpha, row_ptr, eidx, esrc, hcur);

        hin = hcur;
        hcur = (hcur == h0) ? h1 : h0;
    }

    hipMemsetAsync(gsum, 0, NGRAPH * HIDDEN * 4, stream);
    hipMemsetAsync(gcnt, 0, NGRAPH * 4, stream);
    k_pool<<<((N_NODES * HIDDEN) + 255) / 256, 256, 0, stream>>>(hin, batch, gsum, gcnt);
    k_head<<<NGRAPH, 128, 0, stream>>>(gsum, gcnt, fc1w, fc1b, fc2w, fc2b, arcw, out);
}

// Round 2
// 1646.818 us; speedup vs baseline: 1.2669x; 1.2669x over previous
//
#include <hip/hip_runtime.h>
#include <math.h>

#define N_NODES 20000
#define N_EDGES 160000
#define DIM_IN  128
#define HIDDEN  96
#define NH      6
#define HD      576      // NH*HIDDEN
#define LDQ     1824     // 3*HD + HIDDEN  (Q | K | V | S) row stride
#define NGRAPH  512
#define NCLS    128
#define CHUNK   64       // edges per softmax chunk in fused attention

// ---------------------------------------------------------------------------
// Generic fp32 GEMM: C[M, ncols](+col_off into ldc-stride rows) = A[M,K] @ W[K,ncols] + bias
// 64x64 tile, 256 threads, each thread 4x4. LDS stride 68 to dodge bank conflicts.
// ---------------------------------------------------------------------------
__global__ __launch_bounds__(256) void gemm_bias(
    const float* __restrict__ A, int M, int K,
    const float* __restrict__ W, const float* __restrict__ bias,
    float* __restrict__ C, int ldc, int ncols, int col_off)
{
    __shared__ float As[128 * 68];
    __shared__ float Bs[128 * 68];
    int t  = threadIdx.x;
    int tx = t & 15, ty = t >> 4;
    int m0 = blockIdx.y * 64;
    int n0 = blockIdx.x * 64;
    int K4 = K >> 2;

    // A tile, stored transposed: As[k*68 + r]
    for (int i = t; i < 64 * K4; i += 256) {
        int r = i / K4, k4 = i - r * K4;
        int row = m0 + r;
        float4 v = make_float4(0.f, 0.f, 0.f, 0.f);
        if (row < M) v = *(const float4*)(A + (size_t)row * K + k4 * 4);
        As[(4 * k4 + 0) * 68 + r] = v.x;
        As[(4 * k4 + 1) * 68 + r] = v.y;
        As[(4 * k4 + 2) * 68 + r] = v.z;
        As[(4 * k4 + 3) * 68 + r] = v.w;
    }
    // B tile: Bs[k*68 + c]
    for (int i = t; i < K * 16; i += 256) {
        int k = i >> 4, c4 = i & 15;
        int col = n0 + c4 * 4;
        float4 v = make_float4(0.f, 0.f, 0.f, 0.f);
        if (col < ncols) v = *(const float4*)(W + (size_t)k * ncols + col);
        *(float4*)(&Bs[k * 68 + c4 * 4]) = v;
    }
    __syncthreads();

    float acc[4][4] = {};
    #pragma unroll 4
    for (int k = 0; k < K; k++) {
        float4 a = *(const float4*)(&As[k * 68 + ty * 4]);
        float4 b = *(const float4*)(&Bs[k * 68 + tx * 4]);
        float av[4] = {a.x, a.y, a.z, a.w};
        float bv[4] = {b.x, b.y, b.z, b.w};
        #pragma unroll
        for (int i = 0; i < 4; i++)
            #pragma unroll
            for (int j = 0; j < 4; j++)
                acc[i][j] += av[i] * bv[j];
    }

    int c0 = n0 + tx * 4;
    if (c0 < ncols) {
        float4 bb = *(const float4*)(bias + c0);
        #pragma unroll
        for (int i = 0; i < 4; i++) {
            int row = m0 + ty * 4 + i;
            if (row < M) {
                float4 o;
                o.x = acc[i][0] + bb.x;
                o.y = acc[i][1] + bb.y;
                o.z = acc[i][2] + bb.z;
                o.w = acc[i][3] + bb.w;
                *(float4*)(C + (size_t)row * ldc + col_off + c0) = o;
            }
        }
    }
}

// ---------------------------------------------------------------------------
// CSR construction by destination node
// ---------------------------------------------------------------------------
__global__ void k_deg(const int* __restrict__ edst, int* __restrict__ deg)
{
    int e = blockIdx.x * blockDim.x + threadIdx.x;
    if (e < N_EDGES) atomicAdd(&deg[edst[e]], 1);
}

__global__ __launch_bounds__(1024) void k_scan(const int* __restrict__ deg,
                                               int* __restrict__ row_ptr,
                                               int* __restrict__ cursor)
{
    __shared__ int part[1024];
    int t = threadIdx.x;
    const int chunk = (N_NODES + 1023) / 1024;  // 20
    int b = t * chunk;
    int s = 0;
    for (int i = 0; i < chunk; i++)
        if (b + i < N_NODES) s += deg[b + i];
    part[t] = s;
    __syncthreads();
    for (int o = 1; o < 1024; o <<= 1) {
        int v = (t >= o) ? part[t - o] : 0;
        __syncthreads();
        part[t] += v;
        __syncthreads();
    }
    int run = part[t] - s;  // exclusive prefix
    for (int i = 0; i < chunk; i++) {
        if (b + i < N_NODES) {
            row_ptr[b + i] = run;
            cursor[b + i]  = run;
            run += deg[b + i];
        }
    }
    if (t == 1023) row_ptr[N_NODES] = part[1023];
}

// stores the SOURCE node id (not edge id) in CSR order by destination
__global__ void k_scatter(const int* __restrict__ esrc, const int* __restrict__ edst,
                          int* __restrict__ cursor, int* __restrict__ csrc)
{
    int e = blockIdx.x * blockDim.x + threadIdx.x;
    if (e < N_EDGES) {
        int pos = atomicAdd(&cursor[edst[e]], 1);
        csrc[pos] = esrc[e];
    }
}

// ---------------------------------------------------------------------------
// Fused per-destination-node attention: logits (QK^T/sqrt(d)) + chunked
// online segment-softmax + weighted V aggregation + head-mean + skip + ReLU.
// One block (192 threads, 3 waves) per node. Q[dst] staged in LDS once.
// ---------------------------------------------------------------------------
__global__ __launch_bounds__(192) void node_attn(
    const float* __restrict__ qkv, const int* __restrict__ row_ptr,
    const int* __restrict__ csrc, float* __restrict__ hout)
{
    const int n = blockIdx.x;
    const int t = threadIdx.x;
    const int lane = t & 31;
    const int g = t >> 5;              // head group 0..5

    __shared__ float Qs[HD];
    __shared__ float wbuf[CHUNK * NH]; // logits, then weights
    __shared__ int   srcs[CHUNK];
    __shared__ float m[NH], l[NH], scale[NH], linv[NH];
    __shared__ float arr[HD];

    const int beg = row_ptr[n], end = row_ptr[n + 1];

    // stage Q row of this node
    const float* qrow = qkv + (size_t)n * LDQ;
    Qs[t] = qrow[t]; Qs[t + 192] = qrow[t + 192]; Qs[t + 384] = qrow[t + 384];
    if (t < NH) { m[t] = -1e30f; l[t] = 0.f; }

    const int d0 = t, d1 = t + 192, d2 = t + 384;
    const int h0 = d0 / HIDDEN, h1 = d1 / HIDDEN, h2 = d2 / HIDDEN;
    float a0 = 0.f, a1 = 0.f, a2 = 0.f;

    const float qa = 0.10206207261596577f; // 1/sqrt(96)

    for (int cb = beg; cb < end; cb += CHUNK) {
        const int c = min(CHUNK, end - cb);
        __syncthreads();                       // protect srcs/wbuf reuse
        if (t < c) srcs[t] = csrc[cb + t];
        __syncthreads();

        // pass 1: logits. group g handles head g for all edges of the chunk.
        for (int e = 0; e < c; e++) {
            const float* kk = qkv + (size_t)srcs[e] * LDQ + HD + g * HIDDEN;
            float p = Qs[g * HIDDEN + lane] * kk[lane]
                    + Qs[g * HIDDEN + lane + 32] * kk[lane + 32]
                    + Qs[g * HIDDEN + lane + 64] * kk[lane + 64];
            #pragma unroll
            for (int o = 16; o; o >>= 1) p += __shfl_xor(p, o, 32);
            if (lane == 0) wbuf[e * NH + g] = p * qa;
        }
        __syncthreads();

        // chunk max per head, running-max merge, rescale factor
        if (t < NH) {
            float cm = m[t];
            for (int e = 0; e < c; e++) cm = fmaxf(cm, wbuf[e * NH + t]);
            scale[t] = __expf(m[t] - cm);      // exp(-inf)=0 on first chunk
            m[t] = cm;
            l[t] *= scale[t];
        }
        __syncthreads();

        // rescale accumulators; convert logits->weights; accumulate l
        a0 *= scale[h0]; a1 *= scale[h1]; a2 *= scale[h2];
        float lp = 0.f;
        for (int e = lane; e < c; e += 32) {
            float w = __expf(wbuf[e * NH + g] - m[g]);
            wbuf[e * NH + g] = w;
            lp += w;
        }
        #pragma unroll
        for (int o = 16; o; o >>= 1) lp += __shfl_xor(lp, o, 32);
        if (lane == 0) l[g] += lp;
        __syncthreads();

        // pass 2: weighted V aggregation (w via LDS broadcast)
        for (int e = 0; e < c; e++) {
            const float* v = qkv + (size_t)srcs[e] * LDQ + 2 * HD;
            const float* w = wbuf + e * NH;
            a0 += w[h0] * v[d0];
            a1 += w[h1] * v[d1];
            a2 += w[h2] * v[d2];
        }
    }

    if (t < NH) linv[t] = (l[t] > 0.f) ? 1.0f / l[t] : 0.f;
    __syncthreads();
    arr[d0] = a0 * linv[h0]; arr[d1] = a1 * linv[h1]; arr[d2] = a2 * linv[h2];
    __syncthreads();

    if (t < HIDDEN) {
        float s = (arr[t] + arr[HIDDEN + t] + arr[2 * HIDDEN + t] +
                   arr[3 * HIDDEN + t] + arr[4 * HIDDEN + t] + arr[5 * HIDDEN + t])
                  * (1.0f / 6.0f);
        s += qrow[3 * HD + t];  // skip connection S
        hout[n * HIDDEN + t] = fmaxf(s, 0.0f);
    }
}

// ---------------------------------------------------------------------------
// Global mean pool (sums + counts via atomics)
// ---------------------------------------------------------------------------
__global__ void k_pool(const float* __restrict__ h, const int* __restrict__ batch,
                       float* __restrict__ gsum, int* __restrict__ gcnt)
{
    int i = blockIdx.x * blockDim.x + threadIdx.x;
    if (i >= N_NODES * HIDDEN) return;
    int n = i / HIDDEN, d = i - n * HIDDEN;
    int b = batch[n];
    atomicAdd(&gsum[b * HIDDEN + d], h[i]);
    if (d == 0) atomicAdd(&gcnt[b], 1);
}

// ---------------------------------------------------------------------------
// Head: mean -> fc1+relu -> fc2+relu -> ArcFace cosine logits * 30
// One block of 128 threads per graph.
// ---------------------------------------------------------------------------
__global__ __launch_bounds__(128) void k_head(
    const float* __restrict__ gsum, const int* __restrict__ gcnt,
    const float* __restrict__ fc1w, const float* __restrict__ fc1b,
    const float* __restrict__ fc2w, const float* __restrict__ fc2b,
    const float* __restrict__ arcw, float* __restrict__ out)
{
    int g = blockIdx.x, t = threadIdx.x;
    __shared__ float v0[HIDDEN], v1[HIDDEN], v2[HIDDEN];
    __shared__ float gnorm;
    float cnt = fmaxf((float)gcnt[g], 1.0f);
    if (t < HIDDEN) v0[t] = gsum[g * HIDDEN + t] / cnt;
    __syncthreads();
    if (t < HIDDEN) {
        float s = fc1b[t];
        for (int k = 0; k < HIDDEN; k++) s += v0[k] * fc1w[k * HIDDEN + t];
        v1[t] = fmaxf(s, 0.f);
    }
    __syncthreads();
    if (t < HIDDEN) {
        float s = fc2b[t];
        for (int k = 0; k < HIDDEN; k++) s += v1[k] * fc2w[k * HIDDEN + t];
        v2[t] = fmaxf(s, 0.f);
    }
    __syncthreads();
    if (t == 0) {
        float s = 0.f;
        for (int k = 0; k < HIDDEN; k++) s += v2[k] * v2[k];
        gnorm = sqrtf(s) + 1e-12f;
    }
    __syncthreads();
    if (t < NCLS) {
        float dot = 0.f, wn = 0.f;
        const float* wr = arcw + (size_t)t * HIDDEN;
        for (int k = 0; k < HIDDEN; k++) {
            float w = wr[k];
            dot += w * v2[k];
            wn  += w * w;
        }
        out[g * NCLS + t] = 30.0f * dot / (gnorm * (sqrtf(wn) + 1e-12f));
    }
}

// ---------------------------------------------------------------------------
extern "C" void kernel_launch(void* const* d_in, const int* in_sizes, int n_in,
                              void* d_out, int out_size, void* d_ws, size_t ws_size,
                              hipStream_t stream)
{
    (void)in_sizes; (void)n_in; (void)out_size; (void)ws_size;

    const float* x     = (const float*)d_in[0];
    const int*   ei    = (const int*)d_in[1];
    const int*   batch = (const int*)d_in[2];
    const float* Wq1 = (const float*)d_in[3];  const float* bq1 = (const float*)d_in[4];
    const float* Wk1 = (const float*)d_in[5];  const float* bk1 = (const float*)d_in[6];
    const float* Wv1 = (const float*)d_in[7];  const float* bv1 = (const float*)d_in[8];
    const float* Ws1 = (const float*)d_in[9];  const float* bs1 = (const float*)d_in[10];
    const float* Wq_r = (const float*)d_in[11]; const float* bq_r = (const float*)d_in[12];
    const float* Wk_r = (const float*)d_in[13]; const float* bk_r = (const float*)d_in[14];
    const float* Wv_r = (const float*)d_in[15]; const float* bv_r = (const float*)d_in[16];
    const float* Ws_r = (const float*)d_in[17]; const float* bs_r = (const float*)d_in[18];
    const float* fc1w = (const float*)d_in[19]; const float* fc1b = (const float*)d_in[20];
    const float* fc2w = (const float*)d_in[21]; const float* fc2b = (const float*)d_in[22];
    const float* arcw = (const float*)d_in[23];
    float* out = (float*)d_out;

    const int* esrc = ei;            // edge_index[0]
    const int* edst = ei + N_EDGES;  // edge_index[1]

    char* base = (char*)d_ws;
    size_t off = 0;
    auto alloc = [&](size_t bytes) -> void* {
        off = (off + 255) & ~(size_t)255;
        void* p = base + off;
        off += bytes;
        return p;
    };
    float* qkv     = (float*)alloc((size_t)N_NODES * LDQ * 4);   // ~146 MB
    float* h0      = (float*)alloc((size_t)N_NODES * HIDDEN * 4);
    float* h1      = (float*)alloc((size_t)N_NODES * HIDDEN * 4);
    int*   deg     = (int*)alloc(N_NODES * 4);
    int*   row_ptr = (int*)alloc((N_NODES + 1) * 4);
    int*   cursor  = (int*)alloc(N_NODES * 4);
    int*   csrc    = (int*)alloc(N_EDGES * 4);
    float* gsum    = (float*)alloc(NGRAPH * HIDDEN * 4);
    int*   gcnt    = (int*)alloc(NGRAPH * 4);

    // CSR by destination (graph is identical every call; rebuilt each launch)
    hipMemsetAsync(deg, 0, N_NODES * 4, stream);
    k_deg<<<(N_EDGES + 255) / 256, 256, 0, stream>>>(edst, deg);
    k_scan<<<1, 1024, 0, stream>>>(deg, row_ptr, cursor);
    k_scatter<<<(N_EDGES + 255) / 256, 256, 0, stream>>>(esrc, edst, cursor, csrc);

    const float* hin = x;
    float* hcur = h0;
    for (int L = 0; L < 5; L++) {
        int K = (L == 0) ? DIM_IN : HIDDEN;
        const float *Wq, *bq, *Wk, *bk, *Wv, *bv, *Ws, *bs;
        if (L == 0) {
            Wq = Wq1; bq = bq1; Wk = Wk1; bk = bk1;
            Wv = Wv1; bv = bv1; Ws = Ws1; bs = bs1;
        } else {
            int i = L - 1;
            Wq = Wq_r + (size_t)i * HIDDEN * HD; bq = bq_r + (size_t)i * HD;
            Wk = Wk_r + (size_t)i * HIDDEN * HD; bk = bk_r + (size_t)i * HD;
            Wv = Wv_r + (size_t)i * HIDDEN * HD; bv = bv_r + (size_t)i * HD;
            Ws = Ws_r + (size_t)i * HIDDEN * HIDDEN; bs = bs_r + (size_t)i * HIDDEN;
        }
        dim3 gQ(HD / 64, (N_NODES + 63) / 64);
        gemm_bias<<<gQ, 256, 0, stream>>>(hin, N_NODES, K, Wq, bq, qkv, LDQ, HD, 0);
        gemm_bias<<<gQ, 256, 0, stream>>>(hin, N_NODES, K, Wk, bk, qkv, LDQ, HD, HD);
        gemm_bias<<<gQ, 256, 0, stream>>>(hin, N_NODES, K, Wv, bv, qkv, LDQ, HD, 2 * HD);
        dim3 gS((HIDDEN + 63) / 64, (N_NODES + 63) / 64);
        gemm_bias<<<gS, 256, 0, stream>>>(hin, N_NODES, K, Ws, bs, qkv, LDQ, HIDDEN, 3 * HD);

        node_attn<<<N_NODES, 192, 0, stream>>>(qkv, row_ptr, csrc, hcur);

        hin = hcur;
        hcur = (hcur == h0) ? h1 : h0;
    }

    hipMemsetAsync(gsum, 0, NGRAPH * HIDDEN * 4, stream);
    hipMemsetAsync(gcnt, 0, NGRAPH * 4, stream);
    k_pool<<<((N_NODES * HIDDEN) + 255) / 256, 256, 0, stream>>>(hin, batch, gsum, gcnt);
    k_head<<<NGRAPH, 128, 0, stream>>>(gsum, gcnt, fc1w, fc1b, fc2w, fc2b, arcw, out);
}

// Round 3
// 1168.475 us; speedup vs baseline: 1.7855x; 1.4094x over previous
//
#include <hip/hip_runtime.h>
#include <hip/hip_bf16.h>
#include <math.h>

#define N_NODES 20000
#define N_EDGES 160000
#define DIM_IN  128
#define HIDDEN  96
#define NH      6
#define HD      576      // NH*HIDDEN
#define LDQS    672      // fp32 row: Q(576) | S(96)
#define LDKV    1152     // bf16 row: K(576) | V(576)
#define NGRAPH  512
#define NCLS    128
#define CHUNK   64       // edges per softmax chunk in fused attention

static __device__ __forceinline__ unsigned short f2bf(float f) {
    unsigned int u = __float_as_uint(f);
    unsigned int r = (u + 0x7fffu + ((u >> 16) & 1u)) >> 16;  // RNE
    return (unsigned short)r;
}
static __device__ __forceinline__ float bflo(unsigned int u) { return __uint_as_float(u << 16); }
static __device__ __forceinline__ float bfhi(unsigned int u) { return __uint_as_float(u & 0xffff0000u); }
static __device__ __forceinline__ float bfs(unsigned short u) { return __uint_as_float((unsigned int)u << 16); }

// ---------------------------------------------------------------------------
// Fused QKVS projection GEMM. Tile 128(M) x 64(N), 256 threads, 8x4/thread,
// K staged in chunks of 32. LDS = 25.6 KB -> 6 blocks/CU (24 waves).
// grid.x: col-blocks 0-8 -> Q, 9-17 -> K, 18-26 -> V, 27-28 -> S.
// Q,S written fp32 to qs[LDQS]; K,V written bf16 to kv[LDKV].
// ---------------------------------------------------------------------------
__global__ __launch_bounds__(256) void gemm_qkvs(
    const float* __restrict__ A, int M, int K,
    const float* __restrict__ Wq, const float* __restrict__ bq,
    const float* __restrict__ Wk, const float* __restrict__ bk,
    const float* __restrict__ Wv, const float* __restrict__ bv,
    const float* __restrict__ Ws, const float* __restrict__ bs,
    float* __restrict__ qs, __hip_bfloat16* __restrict__ kv)
{
    __shared__ float As[32 * 132];   // [k][row], padded stride 132
    __shared__ float Bs[32 * 68];    // [k][col], padded stride 68
    const int t  = threadIdx.x;
    const int tx = t & 15, ty = t >> 4;
    const int m0 = blockIdx.y * 128;
    const int cb = blockIdx.x;

    int region, lc0, ncols;
    const float *W, *bias;
    if (cb < 9)       { region = 0; W = Wq; bias = bq; ncols = HD;     lc0 = cb * 64; }
    else if (cb < 18) { region = 1; W = Wk; bias = bk; ncols = HD;     lc0 = (cb - 9) * 64; }
    else if (cb < 27) { region = 2; W = Wv; bias = bv; ncols = HD;     lc0 = (cb - 18) * 64; }
    else              { region = 3; W = Ws; bias = bs; ncols = HIDDEN; lc0 = (cb - 27) * 64; }

    float acc[8][4] = {};

    for (int kc = 0; kc < K; kc += 32) {
        #pragma unroll
        for (int it = 0; it < 4; it++) {           // A chunk: 128 rows x 32 k
            int i = t + it * 256;
            int r = i >> 3, kg = i & 7;
            int row = m0 + r;
            float4 v = make_float4(0.f, 0.f, 0.f, 0.f);
            if (row < M) v = *(const float4*)(A + (size_t)row * K + kc + kg * 4);
            As[(kg * 4 + 0) * 132 + r] = v.x;
            As[(kg * 4 + 1) * 132 + r] = v.y;
            As[(kg * 4 + 2) * 132 + r] = v.z;
            As[(kg * 4 + 3) * 132 + r] = v.w;
        }
        #pragma unroll
        for (int it = 0; it < 2; it++) {           // B chunk: 32 k x 64 cols
            int i = t + it * 256;
            int k = i >> 4, c4 = i & 15;
            int col = lc0 + c4 * 4;
            float4 v = make_float4(0.f, 0.f, 0.f, 0.f);
            if (col < ncols) v = *(const float4*)(W + (size_t)(kc + k) * ncols + col);
            *(float4*)(&Bs[k * 68 + c4 * 4]) = v;
        }
        __syncthreads();

        #pragma unroll 8
        for (int kk = 0; kk < 32; kk++) {
            float4 a0 = *(const float4*)(&As[kk * 132 + ty * 8]);
            float4 a1 = *(const float4*)(&As[kk * 132 + ty * 8 + 4]);
            float4 b  = *(const float4*)(&Bs[kk * 68 + tx * 4]);
            float av[8] = {a0.x, a0.y, a0.z, a0.w, a1.x, a1.y, a1.z, a1.w};
            float bv4[4] = {b.x, b.y, b.z, b.w};
            #pragma unroll
            for (int i = 0; i < 8; i++)
                #pragma unroll
                for (int j = 0; j < 4; j++)
                    acc[i][j] += av[i] * bv4[j];
        }
        __syncthreads();
    }

    int c0 = lc0 + tx * 4;
    if (c0 >= ncols) return;
    float4 bb = *(const float4*)(bias + c0);
    #pragma unroll
    for (int i = 0; i < 8; i++) {
        int row = m0 + ty * 8 + i;
        if (row >= M) break;
        float o0 = acc[i][0] + bb.x, o1 = acc[i][1] + bb.y;
        float o2 = acc[i][2] + bb.z, o3 = acc[i][3] + bb.w;
        if (region == 0) {
            *(float4*)(qs + (size_t)row * LDQS + c0) = make_float4(o0, o1, o2, o3);
        } else if (region == 3) {
            *(float4*)(qs + (size_t)row * LDQS + HD + c0) = make_float4(o0, o1, o2, o3);
        } else {
            int base = (region == 1) ? 0 : HD;
            ushort4 u = make_ushort4(f2bf(o0), f2bf(o1), f2bf(o2), f2bf(o3));
            *(ushort4*)((unsigned short*)kv + (size_t)row * LDKV + base + c0) = u;
        }
    }
}

// ---------------------------------------------------------------------------
// CSR construction by destination node
// ---------------------------------------------------------------------------
__global__ void k_deg(const int* __restrict__ edst, int* __restrict__ deg)
{
    int e = blockIdx.x * blockDim.x + threadIdx.x;
    if (e < N_EDGES) atomicAdd(&deg[edst[e]], 1);
}

__global__ __launch_bounds__(1024) void k_scan(const int* __restrict__ deg,
                                               int* __restrict__ row_ptr,
                                               int* __restrict__ cursor)
{
    __shared__ int part[1024];
    int t = threadIdx.x;
    const int chunk = (N_NODES + 1023) / 1024;  // 20
    int b = t * chunk;
    int s = 0;
    for (int i = 0; i < chunk; i++)
        if (b + i < N_NODES) s += deg[b + i];
    part[t] = s;
    __syncthreads();
    for (int o = 1; o < 1024; o <<= 1) {
        int v = (t >= o) ? part[t - o] : 0;
        __syncthreads();
        part[t] += v;
        __syncthreads();
    }
    int run = part[t] - s;  // exclusive prefix
    for (int i = 0; i < chunk; i++) {
        if (b + i < N_NODES) {
            row_ptr[b + i] = run;
            cursor[b + i]  = run;
            run += deg[b + i];
        }
    }
    if (t == 1023) row_ptr[N_NODES] = part[1023];
}

// stores the SOURCE node id in CSR order by destination
__global__ void k_scatter(const int* __restrict__ esrc, const int* __restrict__ edst,
                          int* __restrict__ cursor, int* __restrict__ csrc)
{
    int e = blockIdx.x * blockDim.x + threadIdx.x;
    if (e < N_EDGES) {
        int pos = atomicAdd(&cursor[edst[e]], 1);
        csrc[pos] = esrc[e];
    }
}

// ---------------------------------------------------------------------------
// Fused per-destination-node attention with bf16 K/V gathers.
// One block (192 threads) per node; Q row staged fp32 in LDS.
// ---------------------------------------------------------------------------
__global__ __launch_bounds__(192) void node_attn(
    const float* __restrict__ qs, const __hip_bfloat16* __restrict__ kv,
    const int* __restrict__ row_ptr, const int* __restrict__ csrc,
    float* __restrict__ hout)
{
    const int n = blockIdx.x;
    const int t = threadIdx.x;
    const int lane = t & 31;
    const int g = t >> 5;              // head group 0..5

    __shared__ float Qs[HD];
    __shared__ float wbuf[CHUNK * NH];
    __shared__ int   srcs[CHUNK];
    __shared__ float m[NH], l[NH], scale[NH], linv[NH];
    __shared__ float arr[HD];

    const int beg = row_ptr[n], end = row_ptr[n + 1];
    const float* qrow = qs + (size_t)n * LDQS;
    Qs[t] = qrow[t]; Qs[t + 192] = qrow[t + 192]; Qs[t + 384] = qrow[t + 384];
    if (t < NH) { m[t] = -1e30f; l[t] = 0.f; }

    const int d0 = t, d1 = t + 192, d2 = t + 384;
    const int h0 = d0 / HIDDEN, h1 = d1 / HIDDEN, h2 = d2 / HIDDEN;
    float a0 = 0.f, a1 = 0.f, a2 = 0.f;
    const float qa = 0.10206207261596577f; // 1/sqrt(96)

    for (int cb = beg; cb < end; cb += CHUNK) {
        const int c = min(CHUNK, end - cb);
        __syncthreads();
        if (t < c) srcs[t] = csrc[cb + t];
        __syncthreads();

        // pass 1: logits; group g = head g. K row read as packed bf16 pairs.
        for (int e = 0; e < c; e++) {
            const unsigned int* kk =
                (const unsigned int*)((const unsigned short*)kv + (size_t)srcs[e] * LDKV + g * HIDDEN);
            unsigned int u = kk[lane];
            float p = Qs[g * HIDDEN + 2 * lane] * bflo(u)
                    + Qs[g * HIDDEN + 2 * lane + 1] * bfhi(u);
            if (lane < 16) {
                unsigned int u2 = kk[32 + lane];
                p += Qs[g * HIDDEN + 64 + 2 * lane] * bflo(u2)
                   + Qs[g * HIDDEN + 65 + 2 * lane] * bfhi(u2);
            }
            #pragma unroll
            for (int o = 16; o; o >>= 1) p += __shfl_xor(p, o, 32);
            if (lane == 0) wbuf[e * NH + g] = p * qa;
        }
        __syncthreads();

        // chunk max per head, running-max merge, rescale factor
        if (t < NH) {
            float cm = m[t];
            for (int e = 0; e < c; e++) cm = fmaxf(cm, wbuf[e * NH + t]);
            scale[t] = __expf(m[t] - cm);
            m[t] = cm;
            l[t] *= scale[t];
        }
        __syncthreads();

        a0 *= scale[h0]; a1 *= scale[h1]; a2 *= scale[h2];
        float lp = 0.f;
        for (int e = lane; e < c; e += 32) {
            float w = __expf(wbuf[e * NH + g] - m[g]);
            wbuf[e * NH + g] = w;
            lp += w;
        }
        #pragma unroll
        for (int o = 16; o; o >>= 1) lp += __shfl_xor(lp, o, 32);
        if (lane == 0) l[g] += lp;
        __syncthreads();

        // pass 2: weighted V aggregation (bf16 V)
        for (int e = 0; e < c; e++) {
            const unsigned short* v = (const unsigned short*)kv + (size_t)srcs[e] * LDKV + HD;
            const float* w = wbuf + e * NH;
            a0 += w[h0] * bfs(v[d0]);
            a1 += w[h1] * bfs(v[d1]);
            a2 += w[h2] * bfs(v[d2]);
        }
    }

    if (t < NH) linv[t] = (l[t] > 0.f) ? 1.0f / l[t] : 0.f;
    __syncthreads();
    arr[d0] = a0 * linv[h0]; arr[d1] = a1 * linv[h1]; arr[d2] = a2 * linv[h2];
    __syncthreads();

    if (t < HIDDEN) {
        float s = (arr[t] + arr[HIDDEN + t] + arr[2 * HIDDEN + t] +
                   arr[3 * HIDDEN + t] + arr[4 * HIDDEN + t] + arr[5 * HIDDEN + t])
                  * (1.0f / 6.0f);
        s += qrow[HD + t];  // skip connection S (fp32)
        hout[n * HIDDEN + t] = fmaxf(s, 0.0f);
    }
}

// ---------------------------------------------------------------------------
__global__ void k_pool(const float* __restrict__ h, const int* __restrict__ batch,
                       float* __restrict__ gsum, int* __restrict__ gcnt)
{
    int i = blockIdx.x * blockDim.x + threadIdx.x;
    if (i >= N_NODES * HIDDEN) return;
    int n = i / HIDDEN, d = i - n * HIDDEN;
    int b = batch[n];
    atomicAdd(&gsum[b * HIDDEN + d], h[i]);
    if (d == 0) atomicAdd(&gcnt[b], 1);
}

__global__ __launch_bounds__(128) void k_head(
    const float* __restrict__ gsum, const int* __restrict__ gcnt,
    const float* __restrict__ fc1w, const float* __restrict__ fc1b,
    const float* __restrict__ fc2w, const float* __restrict__ fc2b,
    const float* __restrict__ arcw, float* __restrict__ out)
{
    int g = blockIdx.x, t = threadIdx.x;
    __shared__ float v0[HIDDEN], v1[HIDDEN], v2[HIDDEN];
    __shared__ float gnorm;
    float cnt = fmaxf((float)gcnt[g], 1.0f);
    if (t < HIDDEN) v0[t] = gsum[g * HIDDEN + t] / cnt;
    __syncthreads();
    if (t < HIDDEN) {
        float s = fc1b[t];
        for (int k = 0; k < HIDDEN; k++) s += v0[k] * fc1w[k * HIDDEN + t];
        v1[t] = fmaxf(s, 0.f);
    }
    __syncthreads();
    if (t < HIDDEN) {
        float s = fc2b[t];
        for (int k = 0; k < HIDDEN; k++) s += v1[k] * fc2w[k * HIDDEN + t];
        v2[t] = fmaxf(s, 0.f);
    }
    __syncthreads();
    if (t == 0) {
        float s = 0.f;
        for (int k = 0; k < HIDDEN; k++) s += v2[k] * v2[k];
        gnorm = sqrtf(s) + 1e-12f;
    }
    __syncthreads();
    if (t < NCLS) {
        float dot = 0.f, wn = 0.f;
        const float* wr = arcw + (size_t)t * HIDDEN;
        for (int k = 0; k < HIDDEN; k++) {
            float w = wr[k];
            dot += w * v2[k];
            wn  += w * w;
        }
        out[g * NCLS + t] = 30.0f * dot / (gnorm * (sqrtf(wn) + 1e-12f));
    }
}

// ---------------------------------------------------------------------------
extern "C" void kernel_launch(void* const* d_in, const int* in_sizes, int n_in,
                              void* d_out, int out_size, void* d_ws, size_t ws_size,
                              hipStream_t stream)
{
    (void)in_sizes; (void)n_in; (void)out_size; (void)ws_size;

    const float* x     = (const float*)d_in[0];
    const int*   ei    = (const int*)d_in[1];
    const int*   batch = (const int*)d_in[2];
    const float* Wq1 = (const float*)d_in[3];  const float* bq1 = (const float*)d_in[4];
    const float* Wk1 = (const float*)d_in[5];  const float* bk1 = (const float*)d_in[6];
    const float* Wv1 = (const float*)d_in[7];  const float* bv1 = (const float*)d_in[8];
    const float* Ws1 = (const float*)d_in[9];  const float* bs1 = (const float*)d_in[10];
    const float* Wq_r = (const float*)d_in[11]; const float* bq_r = (const float*)d_in[12];
    const float* Wk_r = (const float*)d_in[13]; const float* bk_r = (const float*)d_in[14];
    const float* Wv_r = (const float*)d_in[15]; const float* bv_r = (const float*)d_in[16];
    const float* Ws_r = (const float*)d_in[17]; const float* bs_r = (const float*)d_in[18];
    const float* fc1w = (const float*)d_in[19]; const float* fc1b = (const float*)d_in[20];
    const float* fc2w = (const float*)d_in[21]; const float* fc2b = (const float*)d_in[22];
    const float* arcw = (const float*)d_in[23];
    float* out = (float*)d_out;

    const int* esrc = ei;            // edge_index[0]
    const int* edst = ei + N_EDGES;  // edge_index[1]

    char* base = (char*)d_ws;
    size_t off = 0;
    auto alloc = [&](size_t bytes) -> void* {
        off = (off + 255) & ~(size_t)255;
        void* p = base + off;
        off += bytes;
        return p;
    };
    float*           qs  = (float*)alloc((size_t)N_NODES * LDQS * 4);            // ~53.8 MB
    __hip_bfloat16*  kv  = (__hip_bfloat16*)alloc((size_t)N_NODES * LDKV * 2);   // ~46.1 MB
    float* h0      = (float*)alloc((size_t)N_NODES * HIDDEN * 4);
    float* h1      = (float*)alloc((size_t)N_NODES * HIDDEN * 4);
    int*   deg     = (int*)alloc(N_NODES * 4);
    int*   row_ptr = (int*)alloc((N_NODES + 1) * 4);
    int*   cursor  = (int*)alloc(N_NODES * 4);
    int*   csrc    = (int*)alloc(N_EDGES * 4);
    float* gsum    = (float*)alloc(NGRAPH * HIDDEN * 4);
    int*   gcnt    = (int*)alloc(NGRAPH * 4);

    // CSR by destination
    hipMemsetAsync(deg, 0, N_NODES * 4, stream);
    k_deg<<<(N_EDGES + 255) / 256, 256, 0, stream>>>(edst, deg);
    k_scan<<<1, 1024, 0, stream>>>(deg, row_ptr, cursor);
    k_scatter<<<(N_EDGES + 255) / 256, 256, 0, stream>>>(esrc, edst, cursor, csrc);

    const float* hin = x;
    float* hcur = h0;
    for (int L = 0; L < 5; L++) {
        int K = (L == 0) ? DIM_IN : HIDDEN;
        const float *Wq, *bq, *Wk, *bk, *Wv, *bv, *Ws, *bs;
        if (L == 0) {
            Wq = Wq1; bq = bq1; Wk = Wk1; bk = bk1;
            Wv = Wv1; bv = bv1; Ws = Ws1; bs = bs1;
        } else {
            int i = L - 1;
            Wq = Wq_r + (size_t)i * HIDDEN * HD; bq = bq_r + (size_t)i * HD;
            Wk = Wk_r + (size_t)i * HIDDEN * HD; bk = bk_r + (size_t)i * HD;
            Wv = Wv_r + (size_t)i * HIDDEN * HD; bv = bv_r + (size_t)i * HD;
            Ws = Ws_r + (size_t)i * HIDDEN * HIDDEN; bs = bs_r + (size_t)i * HIDDEN;
        }
        dim3 g(29, (N_NODES + 127) / 128);
        gemm_qkvs<<<g, 256, 0, stream>>>(hin, N_NODES, K,
                                         Wq, bq, Wk, bk, Wv, bv, Ws, bs, qs, kv);
        node_attn<<<N_NODES, 192, 0, stream>>>(qs, kv, row_ptr, csrc, hcur);
        hin = hcur;
        hcur = (hcur == h0) ? h1 : h0;
    }

    hipMemsetAsync(gsum, 0, NGRAPH * HIDDEN * 4, stream);
    hipMemsetAsync(gcnt, 0, NGRAPH * 4, stream);
    k_pool<<<((N_NODES * HIDDEN) + 255) / 256, 256, 0, stream>>>(hin, batch, gsum, gcnt);
    k_head<<<NGRAPH, 128, 0, stream>>>(gsum, gcnt, fc1w, fc1b, fc2w, fc2b, arcw, out);
}

// Round 4
// 1084.806 us; speedup vs baseline: 1.9232x; 1.0771x over previous
//
#include <hip/hip_runtime.h>
#include <math.h>

#define N_NODES 20000
#define N_EDGES 160000
#define DIM_IN  128
#define HIDDEN  96
#define NH      6
#define HD      576      // NH*HIDDEN
#define LDQS    672      // fp32 row: Q(576) | S(96)
#define LDKV    1152     // bf16 row: K(576) | V(576)
#define NALL    1824     // HD*3 + HIDDEN (concat QKVS output cols)
#define NGRAPH  512
#define NCLS    128
#define CHUNK   64

typedef unsigned short ushort_t;
typedef __attribute__((ext_vector_type(8))) short bf16x8;
typedef __attribute__((ext_vector_type(4))) float f32x4;

static __device__ __forceinline__ ushort_t f2bf(float f) {
    unsigned int u = __float_as_uint(f);
    return (ushort_t)((u + 0x7fffu + ((u >> 16) & 1u)) >> 16);  // RNE
}
static __device__ __forceinline__ float bfs(ushort_t u) { return __uint_as_float((unsigned int)u << 16); }
static __device__ __forceinline__ float bflo(unsigned int u) { return __uint_as_float(u << 16); }
static __device__ __forceinline__ float bfhi(unsigned int u) { return __uint_as_float(u & 0xffff0000u); }

// ---------------------------------------------------------------------------
// fp32 -> bf16 casts
// ---------------------------------------------------------------------------
__global__ void k_cvt(const float* __restrict__ src, ushort_t* __restrict__ dst, int n)
{
    int i = blockIdx.x * blockDim.x + threadIdx.x;
    if (i < n) dst[i] = f2bf(src[i]);
}

// Build concatenated bf16 weight matrix [K x 1824] = [Wq | Wk | Wv | Ws]
__global__ void k_cvt_w(const float* __restrict__ Wq, const float* __restrict__ Wk,
                        const float* __restrict__ Wv, const float* __restrict__ Ws,
                        int K, ushort_t* __restrict__ dst)
{
    int i = blockIdx.x * blockDim.x + threadIdx.x;
    if (i >= K * NALL) return;
    int k = i / NALL, n = i - k * NALL;
    float v;
    if (n < 576)       v = Wq[(size_t)k * HD + n];
    else if (n < 1152) v = Wk[(size_t)k * HD + (n - 576)];
    else if (n < 1728) v = Wv[(size_t)k * HD + (n - 1152)];
    else               v = Ws[(size_t)k * HIDDEN + (n - 1728)];
    dst[i] = f2bf(v);
}

// ---------------------------------------------------------------------------
// bf16 MFMA fused QKVS projection. Block tile 128(M) x 96(N), 256 threads =
// 4 waves in 2x2; each wave 64x48 = 4x3 mfma_f32_16x16x32_bf16 tiles.
// Whole K (<=128) staged in LDS once (A row-major, B transposed, +8 pad).
// grid.x = 19 col-blocks of 96: 0-5 Q, 6-11 K, 12-17 V, 18 S.
// ---------------------------------------------------------------------------
__global__ __launch_bounds__(256) void gemm_qkvs_mfma(
    const ushort_t* __restrict__ A, int M, int K,
    const ushort_t* __restrict__ Wb,
    const float* __restrict__ bq, const float* __restrict__ bk,
    const float* __restrict__ bv, const float* __restrict__ bs,
    float* __restrict__ qs, ushort_t* __restrict__ kv)
{
    __shared__ __align__(16) ushort_t As[128 * 136];
    __shared__ __align__(16) ushort_t Bs[96 * 136];
    const int t    = threadIdx.x;
    const int lane = t & 63;
    const int w    = t >> 6;
    const int wm   = w & 1, wn = w >> 1;
    const int quad = lane >> 4;
    const int l16  = lane & 15;
    const int m0   = blockIdx.y * 128;
    const int rb   = blockIdx.x;          // 0..18
    const int n0   = rb * 96;
    const int LDA  = K + 8;
    const int K8   = K >> 3;

    // stage A tile [128 x K] bf16, 16B vectors, zero-fill OOB rows
    for (int idx = t; idx < 128 * K8; idx += 256) {
        int r = idx / K8, kc = idx - r * K8;
        int row = m0 + r;
        uint4 v = make_uint4(0u, 0u, 0u, 0u);
        if (row < M) v = *(const uint4*)(A + (size_t)row * K + kc * 8);
        *(uint4*)(&As[r * LDA + kc * 8]) = v;
    }
    // stage B tile transposed: Bs[c][k] = Wb[k][n0+c]
    for (int idx = t; idx < 96 * K; idx += 256) {
        int k = idx / 96, c = idx - k * 96;
        Bs[c * LDA + k] = Wb[(size_t)k * NALL + n0 + c];
    }
    __syncthreads();

    f32x4 acc[4][3] = {};
    for (int ks = 0; ks < K; ks += 32) {
        bf16x8 af[4], bfv[3];
        #pragma unroll
        for (int i = 0; i < 4; i++)
            af[i] = *(const bf16x8*)(&As[(wm * 64 + i * 16 + l16) * LDA + ks + quad * 8]);
        #pragma unroll
        for (int j = 0; j < 3; j++)
            bfv[j] = *(const bf16x8*)(&Bs[(wn * 48 + j * 16 + l16) * LDA + ks + quad * 8]);
        #pragma unroll
        for (int i = 0; i < 4; i++)
            #pragma unroll
            for (int j = 0; j < 3; j++)
                acc[i][j] = __builtin_amdgcn_mfma_f32_16x16x32_bf16(af[i], bfv[j], acc[i][j], 0, 0, 0);
    }

    // epilogue: bias + route to fp32 qs (Q,S) or bf16 kv (K,V)
    int reg; const float* biasp;
    if (rb < 6)       { reg = 0; biasp = bq; }
    else if (rb < 12) { reg = 1; biasp = bk; }
    else if (rb < 18) { reg = 2; biasp = bv; }
    else              { reg = 3; biasp = bs; }
    const int colbase = (reg == 3) ? 0 : (rb - reg * 6) * 96;
    float bj[3]; int colr[3];
    #pragma unroll
    for (int j = 0; j < 3; j++) {
        colr[j] = colbase + wn * 48 + j * 16 + l16;
        bj[j] = biasp[colr[j]];
    }
    #pragma unroll
    for (int i = 0; i < 4; i++) {
        #pragma unroll
        for (int r = 0; r < 4; r++) {
            int row = m0 + wm * 64 + i * 16 + quad * 4 + r;
            if (row >= M) continue;
            #pragma unroll
            for (int j = 0; j < 3; j++) {
                float v = acc[i][j][r] + bj[j];
                if (reg == 0)      qs[(size_t)row * LDQS + colr[j]] = v;
                else if (reg == 3) qs[(size_t)row * LDQS + HD + colr[j]] = v;
                else if (reg == 1) kv[(size_t)row * LDKV + colr[j]] = f2bf(v);
                else               kv[(size_t)row * LDKV + HD + colr[j]] = f2bf(v);
            }
        }
    }
}

// ---------------------------------------------------------------------------
// CSR construction by destination node
// ---------------------------------------------------------------------------
__global__ void k_deg(const int* __restrict__ edst, int* __restrict__ deg)
{
    int e = blockIdx.x * blockDim.x + threadIdx.x;
    if (e < N_EDGES) atomicAdd(&deg[edst[e]], 1);
}

__global__ __launch_bounds__(1024) void k_scan(const int* __restrict__ deg,
                                               int* __restrict__ row_ptr,
                                               int* __restrict__ cursor)
{
    __shared__ int part[1024];
    int t = threadIdx.x;
    const int chunk = (N_NODES + 1023) / 1024;  // 20
    int b = t * chunk;
    int s = 0;
    for (int i = 0; i < chunk; i++)
        if (b + i < N_NODES) s += deg[b + i];
    part[t] = s;
    __syncthreads();
    for (int o = 1; o < 1024; o <<= 1) {
        int v = (t >= o) ? part[t - o] : 0;
        __syncthreads();
        part[t] += v;
        __syncthreads();
    }
    int run = part[t] - s;
    for (int i = 0; i < chunk; i++) {
        if (b + i < N_NODES) {
            row_ptr[b + i] = run;
            cursor[b + i]  = run;
            run += deg[b + i];
        }
    }
    if (t == 1023) row_ptr[N_NODES] = part[1023];
}

__global__ void k_scatter(const int* __restrict__ esrc, const int* __restrict__ edst,
                          int* __restrict__ cursor, int* __restrict__ csrc)
{
    int e = blockIdx.x * blockDim.x + threadIdx.x;
    if (e < N_EDGES) {
        int pos = atomicAdd(&cursor[edst[e]], 1);
        csrc[pos] = esrc[e];
    }
}

// ---------------------------------------------------------------------------
// Fused per-destination-node attention with bf16 K/V gathers.
// Outputs h in bf16 (next layer's GEMM input) and fp32 (pool path).
// ---------------------------------------------------------------------------
__global__ __launch_bounds__(192) void node_attn(
    const float* __restrict__ qs, const ushort_t* __restrict__ kv,
    const int* __restrict__ row_ptr, const int* __restrict__ csrc,
    ushort_t* __restrict__ hb, float* __restrict__ hf)
{
    const int n = blockIdx.x;
    const int t = threadIdx.x;
    const int lane = t & 31;
    const int g = t >> 5;

    __shared__ float Qs[HD];
    __shared__ float wbuf[CHUNK * NH];
    __shared__ int   srcs[CHUNK];
    __shared__ float m[NH], l[NH], scale[NH], linv[NH];
    __shared__ float arr[HD];

    const int beg = row_ptr[n], end = row_ptr[n + 1];
    const float* qrow = qs + (size_t)n * LDQS;
    Qs[t] = qrow[t]; Qs[t + 192] = qrow[t + 192]; Qs[t + 384] = qrow[t + 384];
    if (t < NH) { m[t] = -1e30f; l[t] = 0.f; }

    const int d0 = t, d1 = t + 192, d2 = t + 384;
    const int h0 = d0 / HIDDEN, h1 = d1 / HIDDEN, h2 = d2 / HIDDEN;
    float a0 = 0.f, a1 = 0.f, a2 = 0.f;
    const float qa = 0.10206207261596577f; // 1/sqrt(96)

    for (int cb = beg; cb < end; cb += CHUNK) {
        const int c = min(CHUNK, end - cb);
        __syncthreads();
        if (t < c) srcs[t] = csrc[cb + t];
        __syncthreads();

        for (int e = 0; e < c; e++) {
            const unsigned int* kk =
                (const unsigned int*)(kv + (size_t)srcs[e] * LDKV + g * HIDDEN);
            unsigned int u = kk[lane];
            float p = Qs[g * HIDDEN + 2 * lane] * bflo(u)
                    + Qs[g * HIDDEN + 2 * lane + 1] * bfhi(u);
            if (lane < 16) {
                unsigned int u2 = kk[32 + lane];
                p += Qs[g * HIDDEN + 64 + 2 * lane] * bflo(u2)
                   + Qs[g * HIDDEN + 65 + 2 * lane] * bfhi(u2);
            }
            #pragma unroll
            for (int o = 16; o; o >>= 1) p += __shfl_xor(p, o, 32);
            if (lane == 0) wbuf[e * NH + g] = p * qa;
        }
        __syncthreads();

        if (t < NH) {
            float cm = m[t];
            for (int e = 0; e < c; e++) cm = fmaxf(cm, wbuf[e * NH + t]);
            scale[t] = __expf(m[t] - cm);
            m[t] = cm;
            l[t] *= scale[t];
        }
        __syncthreads();

        a0 *= scale[h0]; a1 *= scale[h1]; a2 *= scale[h2];
        float lp = 0.f;
        for (int e = lane; e < c; e += 32) {
            float w2 = __expf(wbuf[e * NH + g] - m[g]);
            wbuf[e * NH + g] = w2;
            lp += w2;
        }
        #pragma unroll
        for (int o = 16; o; o >>= 1) lp += __shfl_xor(lp, o, 32);
        if (lane == 0) l[g] += lp;
        __syncthreads();

        for (int e = 0; e < c; e++) {
            const ushort_t* v = kv + (size_t)srcs[e] * LDKV + HD;
            const float* w2 = wbuf + e * NH;
            a0 += w2[h0] * bfs(v[d0]);
            a1 += w2[h1] * bfs(v[d1]);
            a2 += w2[h2] * bfs(v[d2]);
        }
    }

    if (t < NH) linv[t] = (l[t] > 0.f) ? 1.0f / l[t] : 0.f;
    __syncthreads();
    arr[d0] = a0 * linv[h0]; arr[d1] = a1 * linv[h1]; arr[d2] = a2 * linv[h2];
    __syncthreads();

    if (t < HIDDEN) {
        float s = (arr[t] + arr[HIDDEN + t] + arr[2 * HIDDEN + t] +
                   arr[3 * HIDDEN + t] + arr[4 * HIDDEN + t] + arr[5 * HIDDEN + t])
                  * (1.0f / 6.0f);
        s += qrow[HD + t];
        s = fmaxf(s, 0.0f);
        hb[n * HIDDEN + t] = f2bf(s);
        hf[n * HIDDEN + t] = s;
    }
}

// ---------------------------------------------------------------------------
__global__ void k_pool(const float* __restrict__ h, const int* __restrict__ batch,
                       float* __restrict__ gsum, int* __restrict__ gcnt)
{
    int i = blockIdx.x * blockDim.x + threadIdx.x;
    if (i >= N_NODES * HIDDEN) return;
    int n = i / HIDDEN, d = i - n * HIDDEN;
    int b = batch[n];
    atomicAdd(&gsum[b * HIDDEN + d], h[i]);
    if (d == 0) atomicAdd(&gcnt[b], 1);
}

__global__ __launch_bounds__(128) void k_head(
    const float* __restrict__ gsum, const int* __restrict__ gcnt,
    const float* __restrict__ fc1w, const float* __restrict__ fc1b,
    const float* __restrict__ fc2w, const float* __restrict__ fc2b,
    const float* __restrict__ arcw, float* __restrict__ out)
{
    int g = blockIdx.x, t = threadIdx.x;
    __shared__ float v0[HIDDEN], v1[HIDDEN], v2[HIDDEN];
    __shared__ float gnorm;
    float cnt = fmaxf((float)gcnt[g], 1.0f);
    if (t < HIDDEN) v0[t] = gsum[g * HIDDEN + t] / cnt;
    __syncthreads();
    if (t < HIDDEN) {
        float s = fc1b[t];
        for (int k = 0; k < HIDDEN; k++) s += v0[k] * fc1w[k * HIDDEN + t];
        v1[t] = fmaxf(s, 0.f);
    }
    __syncthreads();
    if (t < HIDDEN) {
        float s = fc2b[t];
        for (int k = 0; k < HIDDEN; k++) s += v1[k] * fc2w[k * HIDDEN + t];
        v2[t] = fmaxf(s, 0.f);
    }
    __syncthreads();
    if (t == 0) {
        float s = 0.f;
        for (int k = 0; k < HIDDEN; k++) s += v2[k] * v2[k];
        gnorm = sqrtf(s) + 1e-12f;
    }
    __syncthreads();
    if (t < NCLS) {
        float dot = 0.f, wn = 0.f;
        const float* wr = arcw + (size_t)t * HIDDEN;
        for (int k = 0; k < HIDDEN; k++) {
            float w = wr[k];
            dot += w * v2[k];
            wn  += w * w;
        }
        out[g * NCLS + t] = 30.0f * dot / (gnorm * (sqrtf(wn) + 1e-12f));
    }
}

// ---------------------------------------------------------------------------
extern "C" void kernel_launch(void* const* d_in, const int* in_sizes, int n_in,
                              void* d_out, int out_size, void* d_ws, size_t ws_size,
                              hipStream_t stream)
{
    (void)in_sizes; (void)n_in; (void)out_size; (void)ws_size;

    const float* x     = (const float*)d_in[0];
    const int*   ei    = (const int*)d_in[1];
    const int*   batch = (const int*)d_in[2];
    const float* Wq1 = (const float*)d_in[3];  const float* bq1 = (const float*)d_in[4];
    const float* Wk1 = (const float*)d_in[5];  const float* bk1 = (const float*)d_in[6];
    const float* Wv1 = (const float*)d_in[7];  const float* bv1 = (const float*)d_in[8];
    const float* Ws1 = (const float*)d_in[9];  const float* bs1 = (const float*)d_in[10];
    const float* Wq_r = (const float*)d_in[11]; const float* bq_r = (const float*)d_in[12];
    const float* Wk_r = (const float*)d_in[13]; const float* bk_r = (const float*)d_in[14];
    const float* Wv_r = (const float*)d_in[15]; const float* bv_r = (const float*)d_in[16];
    const float* Ws_r = (const float*)d_in[17]; const float* bs_r = (const float*)d_in[18];
    const float* fc1w = (const float*)d_in[19]; const float* fc1b = (const float*)d_in[20];
    const float* fc2w = (const float*)d_in[21]; const float* fc2b = (const float*)d_in[22];
    const float* arcw = (const float*)d_in[23];
    float* out = (float*)d_out;

    const int* esrc = ei;
    const int* edst = ei + N_EDGES;

    char* base = (char*)d_ws;
    size_t off = 0;
    auto alloc = [&](size_t bytes) -> void* {
        off = (off + 255) & ~(size_t)255;
        void* p = base + off;
        off += bytes;
        return p;
    };
    float*    qs  = (float*)alloc((size_t)N_NODES * LDQS * 4);      // ~53.8 MB
    ushort_t* kv  = (ushort_t*)alloc((size_t)N_NODES * LDKV * 2);   // ~46.1 MB
    ushort_t* xb  = (ushort_t*)alloc((size_t)N_NODES * DIM_IN * 2);
    ushort_t* hb0 = (ushort_t*)alloc((size_t)N_NODES * HIDDEN * 2);
    ushort_t* hb1 = (ushort_t*)alloc((size_t)N_NODES * HIDDEN * 2);
    float*    hf  = (float*)alloc((size_t)N_NODES * HIDDEN * 4);
    ushort_t* Wb0 = (ushort_t*)alloc((size_t)DIM_IN * NALL * 2);
    ushort_t* Wbr = (ushort_t*)alloc((size_t)4 * HIDDEN * NALL * 2);
    int*   deg     = (int*)alloc(N_NODES * 4);
    int*   row_ptr = (int*)alloc((N_NODES + 1) * 4);
    int*   cursor  = (int*)alloc(N_NODES * 4);
    int*   csrc    = (int*)alloc(N_EDGES * 4);
    float* gsum    = (float*)alloc(NGRAPH * HIDDEN * 4);
    int*   gcnt    = (int*)alloc(NGRAPH * 4);

    // bf16 conversions
    k_cvt<<<(N_NODES * DIM_IN + 255) / 256, 256, 0, stream>>>(x, xb, N_NODES * DIM_IN);
    k_cvt_w<<<(DIM_IN * NALL + 255) / 256, 256, 0, stream>>>(Wq1, Wk1, Wv1, Ws1, DIM_IN, Wb0);
    for (int i = 0; i < 4; i++) {
        k_cvt_w<<<(HIDDEN * NALL + 255) / 256, 256, 0, stream>>>(
            Wq_r + (size_t)i * HIDDEN * HD, Wk_r + (size_t)i * HIDDEN * HD,
            Wv_r + (size_t)i * HIDDEN * HD, Ws_r + (size_t)i * HIDDEN * HIDDEN,
            HIDDEN, Wbr + (size_t)i * HIDDEN * NALL);
    }

    // CSR by destination
    hipMemsetAsync(deg, 0, N_NODES * 4, stream);
    k_deg<<<(N_EDGES + 255) / 256, 256, 0, stream>>>(edst, deg);
    k_scan<<<1, 1024, 0, stream>>>(deg, row_ptr, cursor);
    k_scatter<<<(N_EDGES + 255) / 256, 256, 0, stream>>>(esrc, edst, cursor, csrc);

    const ushort_t* Ain = xb;
    ushort_t* hbcur = hb0;
    for (int L = 0; L < 5; L++) {
        int K = (L == 0) ? DIM_IN : HIDDEN;
        const ushort_t* Wb = (L == 0) ? Wb0 : (Wbr + (size_t)(L - 1) * HIDDEN * NALL);
        const float *bq, *bk, *bv, *bs;
        if (L == 0) { bq = bq1; bk = bk1; bv = bv1; bs = bs1; }
        else {
            int i = L - 1;
            bq = bq_r + (size_t)i * HD; bk = bk_r + (size_t)i * HD;
            bv = bv_r + (size_t)i * HD; bs = bs_r + (size_t)i * HIDDEN;
        }
        dim3 g(19, (N_NODES + 127) / 128);
        gemm_qkvs_mfma<<<g, 256, 0, stream>>>(Ain, N_NODES, K, Wb,
                                              bq, bk, bv, bs, qs, kv);
        node_attn<<<N_NODES, 192, 0, stream>>>(qs, kv, row_ptr, csrc, hbcur, hf);
        Ain = hbcur;
        hbcur = (hbcur == hb0) ? hb1 : hb0;
    }

    hipMemsetAsync(gsum, 0, NGRAPH * HIDDEN * 4, stream);
    hipMemsetAsync(gcnt, 0, NGRAPH * 4, stream);
    k_pool<<<((N_NODES * HIDDEN) + 255) / 256, 256, 0, stream>>>(hf, batch, gsum, gcnt);
    k_head<<<NGRAPH, 128, 0, stream>>>(gsum, gcnt, fc1w, fc1b, fc2w, fc2b, arcw, out);
}

// Round 5
// 961.143 us; speedup vs baseline: 2.1707x; 1.1287x over previous
//
#include <hip/hip_runtime.h>
#include <math.h>

#define N_NODES 20000
#define N_EDGES 160000
#define DIM_IN  128
#define HIDDEN  96
#define NH      6
#define HD      576      // NH*HIDDEN
#define LDQS    672      // fp32 row: Q(576) | S(96)
#define LDKV    1152     // bf16 row: K(576) | V(576)
#define NALL    1824     // HD*3 + HIDDEN (concat QKVS output cols)
#define NGRAPH  512
#define NCLS    128
#define CHUNK   32       // edges per softmax chunk (= lane width of pass 1)

typedef unsigned short ushort_t;
typedef __attribute__((ext_vector_type(8))) short bf16x8;
typedef __attribute__((ext_vector_type(4))) float f32x4;

static __device__ __forceinline__ ushort_t f2bf(float f) {
    unsigned int u = __float_as_uint(f);
    return (ushort_t)((u + 0x7fffu + ((u >> 16) & 1u)) >> 16);  // RNE
}
static __device__ __forceinline__ float bfs(ushort_t u) { return __uint_as_float((unsigned int)u << 16); }
static __device__ __forceinline__ float bflo(unsigned int u) { return __uint_as_float(u << 16); }
static __device__ __forceinline__ float bfhi(unsigned int u) { return __uint_as_float(u & 0xffff0000u); }

// ---------------------------------------------------------------------------
__global__ void k_cvt(const float* __restrict__ src, ushort_t* __restrict__ dst, int n)
{
    int i = blockIdx.x * blockDim.x + threadIdx.x;
    if (i < n) dst[i] = f2bf(src[i]);
}

// Build concatenated bf16 weight matrix [K x 1824] = [Wq | Wk | Wv | Ws]
__global__ void k_cvt_w(const float* __restrict__ Wq, const float* __restrict__ Wk,
                        const float* __restrict__ Wv, const float* __restrict__ Ws,
                        int K, ushort_t* __restrict__ dst)
{
    int i = blockIdx.x * blockDim.x + threadIdx.x;
    if (i >= K * NALL) return;
    int k = i / NALL, n = i - k * NALL;
    float v;
    if (n < 576)       v = Wq[(size_t)k * HD + n];
    else if (n < 1152) v = Wk[(size_t)k * HD + (n - 576)];
    else if (n < 1728) v = Wv[(size_t)k * HD + (n - 1152)];
    else               v = Ws[(size_t)k * HIDDEN + (n - 1728)];
    dst[i] = f2bf(v);
}

// ---------------------------------------------------------------------------
// bf16 MFMA fused QKVS projection. Block 128(M) x 96(N), 256 threads = 4 waves
// (2x2), each wave 64x48 via 4x3 mfma_f32_16x16x32_bf16. K templated so LDS is
// exact: K=96 -> 46.6 KB (3 blocks/CU), K=128 -> 60.9 KB (2 blocks/CU).
// grid.x = 19 col-blocks of 96: 0-5 Q, 6-11 K, 12-17 V, 18 S.
// ---------------------------------------------------------------------------
template<int KDIM>
__global__ __launch_bounds__(256) void gemm_qkvs_mfma(
    const ushort_t* __restrict__ A, int M,
    const ushort_t* __restrict__ Wb,
    const float* __restrict__ bq, const float* __restrict__ bk,
    const float* __restrict__ bv, const float* __restrict__ bs,
    float* __restrict__ qs, ushort_t* __restrict__ kv)
{
    constexpr int LDA = KDIM + 8;
    constexpr int K8  = KDIM >> 3;
    __shared__ __align__(16) ushort_t As[128 * LDA];
    __shared__ __align__(16) ushort_t Bs[96 * LDA];
    const int t    = threadIdx.x;
    const int lane = t & 63;
    const int w    = t >> 6;
    const int wm   = w & 1, wn = w >> 1;
    const int quad = lane >> 4;
    const int l16  = lane & 15;
    const int m0   = blockIdx.y * 128;
    const int rb   = blockIdx.x;          // 0..18
    const int n0   = rb * 96;

    // stage A tile [128 x K] bf16, 16B vectors, zero-fill OOB rows
    for (int idx = t; idx < 128 * K8; idx += 256) {
        int r = idx / K8, kc = idx - r * K8;
        int row = m0 + r;
        uint4 v = make_uint4(0u, 0u, 0u, 0u);
        if (row < M) v = *(const uint4*)(A + (size_t)row * KDIM + kc * 8);
        *(uint4*)(&As[r * LDA + kc * 8]) = v;
    }
    // stage B transposed: Bs[c][k] = Wb[k][n0+c]; ushort4 coalesced loads
    for (int idx = t; idx < 24 * KDIM; idx += 256) {
        int k = idx / 24, c4 = idx - k * 24;
        ushort4 v = *(const ushort4*)(Wb + (size_t)k * NALL + n0 + c4 * 4);
        Bs[(c4 * 4 + 0) * LDA + k] = v.x;
        Bs[(c4 * 4 + 1) * LDA + k] = v.y;
        Bs[(c4 * 4 + 2) * LDA + k] = v.z;
        Bs[(c4 * 4 + 3) * LDA + k] = v.w;
    }
    __syncthreads();

    f32x4 acc[4][3] = {};
    #pragma unroll
    for (int ks = 0; ks < KDIM; ks += 32) {
        bf16x8 af[4], bfv[3];
        #pragma unroll
        for (int i = 0; i < 4; i++)
            af[i] = *(const bf16x8*)(&As[(wm * 64 + i * 16 + l16) * LDA + ks + quad * 8]);
        #pragma unroll
        for (int j = 0; j < 3; j++)
            bfv[j] = *(const bf16x8*)(&Bs[(wn * 48 + j * 16 + l16) * LDA + ks + quad * 8]);
        #pragma unroll
        for (int i = 0; i < 4; i++)
            #pragma unroll
            for (int j = 0; j < 3; j++)
                acc[i][j] = __builtin_amdgcn_mfma_f32_16x16x32_bf16(af[i], bfv[j], acc[i][j], 0, 0, 0);
    }

    int reg; const float* biasp;
    if (rb < 6)       { reg = 0; biasp = bq; }
    else if (rb < 12) { reg = 1; biasp = bk; }
    else if (rb < 18) { reg = 2; biasp = bv; }
    else              { reg = 3; biasp = bs; }
    const int colbase = (reg == 3) ? 0 : (rb - reg * 6) * 96;
    float bj[3]; int colr[3];
    #pragma unroll
    for (int j = 0; j < 3; j++) {
        colr[j] = colbase + wn * 48 + j * 16 + l16;
        bj[j] = biasp[colr[j]];
    }
    #pragma unroll
    for (int i = 0; i < 4; i++) {
        #pragma unroll
        for (int r = 0; r < 4; r++) {
            int row = m0 + wm * 64 + i * 16 + quad * 4 + r;
            if (row >= M) continue;
            #pragma unroll
            for (int j = 0; j < 3; j++) {
                float v = acc[i][j][r] + bj[j];
                if (reg == 0)      qs[(size_t)row * LDQS + colr[j]] = v;
                else if (reg == 3) qs[(size_t)row * LDQS + HD + colr[j]] = v;
                else if (reg == 1) kv[(size_t)row * LDKV + colr[j]] = f2bf(v);
                else               kv[(size_t)row * LDKV + HD + colr[j]] = f2bf(v);
            }
        }
    }
}

// ---------------------------------------------------------------------------
// CSR construction by destination node
// ---------------------------------------------------------------------------
__global__ void k_deg(const int* __restrict__ edst, int* __restrict__ deg)
{
    int e = blockIdx.x * blockDim.x + threadIdx.x;
    if (e < N_EDGES) atomicAdd(&deg[edst[e]], 1);
}

__global__ __launch_bounds__(1024) void k_scan(const int* __restrict__ deg,
                                               int* __restrict__ row_ptr,
                                               int* __restrict__ cursor)
{
    __shared__ int part[1024];
    int t = threadIdx.x;
    const int chunk = (N_NODES + 1023) / 1024;  // 20
    int b = t * chunk;
    int s = 0;
    for (int i = 0; i < chunk; i++)
        if (b + i < N_NODES) s += deg[b + i];
    part[t] = s;
    __syncthreads();
    for (int o = 1; o < 1024; o <<= 1) {
        int v = (t >= o) ? part[t - o] : 0;
        __syncthreads();
        part[t] += v;
        __syncthreads();
    }
    int run = part[t] - s;
    for (int i = 0; i < chunk; i++) {
        if (b + i < N_NODES) {
            row_ptr[b + i] = run;
            cursor[b + i]  = run;
            run += deg[b + i];
        }
    }
    if (t == 1023) row_ptr[N_NODES] = part[1023];
}

__global__ void k_scatter(const int* __restrict__ esrc, const int* __restrict__ edst,
                          int* __restrict__ cursor, int* __restrict__ csrc)
{
    int e = blockIdx.x * blockDim.x + threadIdx.x;
    if (e < N_EDGES) {
        int pos = atomicAdd(&cursor[edst[e]], 1);
        csrc[pos] = esrc[e];
    }
}

// ---------------------------------------------------------------------------
// Fused per-destination-node attention, latency-optimized:
// pass 1: lane l of head-group g owns the FULL dot-96 of edge (cb+l, head g)
//         -> 12 independent uint4 loads per lane, no shfl reduce.
// pass 2: dim-parallel V aggregation, unroll-4 with staged register loads.
// ---------------------------------------------------------------------------
__global__ __launch_bounds__(192) void node_attn(
    const float* __restrict__ qs, const ushort_t* __restrict__ kv,
    const int* __restrict__ row_ptr, const int* __restrict__ csrc,
    ushort_t* __restrict__ hb, float* __restrict__ hf)
{
    const int n = blockIdx.x;
    const int t = threadIdx.x;
    const int lane = t & 31;
    const int g = t >> 5;              // head group 0..5

    __shared__ float Qs[HD];
    __shared__ float wbuf[CHUNK * NH];
    __shared__ int   srcs[CHUNK];
    __shared__ float m[NH], l[NH], scale[NH], linv[NH];
    __shared__ float arr[HD];

    const int beg = row_ptr[n], end = row_ptr[n + 1];
    const float* qrow = qs + (size_t)n * LDQS;
    Qs[t] = qrow[t]; Qs[t + 192] = qrow[t + 192]; Qs[t + 384] = qrow[t + 384];
    if (t < NH) { m[t] = -1e30f; l[t] = 0.f; }

    const int d0 = t, d1 = t + 192, d2 = t + 384;
    const int h0 = d0 / HIDDEN, h1 = d1 / HIDDEN, h2 = d2 / HIDDEN;
    float a0 = 0.f, a1 = 0.f, a2 = 0.f;
    const float qa = 0.10206207261596577f; // 1/sqrt(96)

    for (int cb = beg; cb < end; cb += CHUNK) {
        const int c = min(CHUNK, end - cb);
        __syncthreads();
        if (t < c) srcs[t] = csrc[cb + t];
        __syncthreads();

        // ---- pass 1: per-lane full dot-96 -------------------------------
        if (lane < c) {
            const uint4* kp = (const uint4*)(kv + (size_t)srcs[lane] * LDKV + g * HIDDEN);
            uint4 r[12];
            #pragma unroll
            for (int j = 0; j < 12; j++) r[j] = kp[j];
            float p = 0.f;
            const float* qb = &Qs[g * HIDDEN];
            #pragma unroll
            for (int j = 0; j < 12; j++) {
                unsigned int uu[4] = {r[j].x, r[j].y, r[j].z, r[j].w};
                #pragma unroll
                for (int k2 = 0; k2 < 4; k2++) {
                    p += bflo(uu[k2]) * qb[j * 8 + 2 * k2]
                       + bfhi(uu[k2]) * qb[j * 8 + 2 * k2 + 1];
                }
            }
            wbuf[lane * NH + g] = p * qa;
        }
        __syncthreads();

        // ---- softmax bookkeeping ---------------------------------------
        if (t < NH) {
            float cm = m[t];
            for (int e = 0; e < c; e++) cm = fmaxf(cm, wbuf[e * NH + t]);
            scale[t] = __expf(m[t] - cm);
            m[t] = cm;
            l[t] *= scale[t];
        }
        __syncthreads();

        a0 *= scale[h0]; a1 *= scale[h1]; a2 *= scale[h2];
        float lp = 0.f;
        for (int e = lane; e < c; e += 32) {
            float w2 = __expf(wbuf[e * NH + g] - m[g]);
            wbuf[e * NH + g] = w2;
            lp += w2;
        }
        #pragma unroll
        for (int o = 16; o; o >>= 1) lp += __shfl_xor(lp, o, 32);
        if (lane == 0) l[g] += lp;
        __syncthreads();

        // ---- pass 2: V aggregation, unroll-4 staged loads ---------------
        int e = 0;
        for (; e + 4 <= c; e += 4) {
            ushort_t r0[4], r1[4], r2[4];
            #pragma unroll
            for (int j = 0; j < 4; j++) {
                const ushort_t* v = kv + (size_t)srcs[e + j] * LDKV + HD;
                r0[j] = v[d0]; r1[j] = v[d1]; r2[j] = v[d2];
            }
            #pragma unroll
            for (int j = 0; j < 4; j++) {
                const float* w2 = wbuf + (e + j) * NH;
                a0 += w2[h0] * bfs(r0[j]);
                a1 += w2[h1] * bfs(r1[j]);
                a2 += w2[h2] * bfs(r2[j]);
            }
        }
        for (; e < c; e++) {
            const ushort_t* v = kv + (size_t)srcs[e] * LDKV + HD;
            const float* w2 = wbuf + e * NH;
            a0 += w2[h0] * bfs(v[d0]);
            a1 += w2[h1] * bfs(v[d1]);
            a2 += w2[h2] * bfs(v[d2]);
        }
    }

    if (t < NH) linv[t] = (l[t] > 0.f) ? 1.0f / l[t] : 0.f;
    __syncthreads();
    arr[d0] = a0 * linv[h0]; arr[d1] = a1 * linv[h1]; arr[d2] = a2 * linv[h2];
    __syncthreads();

    if (t < HIDDEN) {
        float s = (arr[t] + arr[HIDDEN + t] + arr[2 * HIDDEN + t] +
                   arr[3 * HIDDEN + t] + arr[4 * HIDDEN + t] + arr[5 * HIDDEN + t])
                  * (1.0f / 6.0f);
        s += qrow[HD + t];
        s = fmaxf(s, 0.0f);
        hb[n * HIDDEN + t] = f2bf(s);
        hf[n * HIDDEN + t] = s;
    }
}

// ---------------------------------------------------------------------------
__global__ void k_pool(const float* __restrict__ h, const int* __restrict__ batch,
                       float* __restrict__ gsum, int* __restrict__ gcnt)
{
    int i = blockIdx.x * blockDim.x + threadIdx.x;
    if (i >= N_NODES * HIDDEN) return;
    int n = i / HIDDEN, d = i - n * HIDDEN;
    int b = batch[n];
    atomicAdd(&gsum[b * HIDDEN + d], h[i]);
    if (d == 0) atomicAdd(&gcnt[b], 1);
}

__global__ __launch_bounds__(128) void k_head(
    const float* __restrict__ gsum, const int* __restrict__ gcnt,
    const float* __restrict__ fc1w, const float* __restrict__ fc1b,
    const float* __restrict__ fc2w, const float* __restrict__ fc2b,
    const float* __restrict__ arcw, float* __restrict__ out)
{
    int g = blockIdx.x, t = threadIdx.x;
    __shared__ float v0[HIDDEN], v1[HIDDEN], v2[HIDDEN];
    __shared__ float gnorm;
    float cnt = fmaxf((float)gcnt[g], 1.0f);
    if (t < HIDDEN) v0[t] = gsum[g * HIDDEN + t] / cnt;
    __syncthreads();
    if (t < HIDDEN) {
        float s = fc1b[t];
        for (int k = 0; k < HIDDEN; k++) s += v0[k] * fc1w[k * HIDDEN + t];
        v1[t] = fmaxf(s, 0.f);
    }
    __syncthreads();
    if (t < HIDDEN) {
        float s = fc2b[t];
        for (int k = 0; k < HIDDEN; k++) s += v1[k] * fc2w[k * HIDDEN + t];
        v2[t] = fmaxf(s, 0.f);
    }
    __syncthreads();
    if (t == 0) {
        float s = 0.f;
        for (int k = 0; k < HIDDEN; k++) s += v2[k] * v2[k];
        gnorm = sqrtf(s) + 1e-12f;
    }
    __syncthreads();
    if (t < NCLS) {
        float dot = 0.f, wn = 0.f;
        const float* wr = arcw + (size_t)t * HIDDEN;
        for (int k = 0; k < HIDDEN; k++) {
            float w = wr[k];
            dot += w * v2[k];
            wn  += w * w;
        }
        out[g * NCLS + t] = 30.0f * dot / (gnorm * (sqrtf(wn) + 1e-12f));
    }
}

// ---------------------------------------------------------------------------
extern "C" void kernel_launch(void* const* d_in, const int* in_sizes, int n_in,
                              void* d_out, int out_size, void* d_ws, size_t ws_size,
                              hipStream_t stream)
{
    (void)in_sizes; (void)n_in; (void)out_size; (void)ws_size;

    const float* x     = (const float*)d_in[0];
    const int*   ei    = (const int*)d_in[1];
    const int*   batch = (const int*)d_in[2];
    const float* Wq1 = (const float*)d_in[3];  const float* bq1 = (const float*)d_in[4];
    const float* Wk1 = (const float*)d_in[5];  const float* bk1 = (const float*)d_in[6];
    const float* Wv1 = (const float*)d_in[7];  const float* bv1 = (const float*)d_in[8];
    const float* Ws1 = (const float*)d_in[9];  const float* bs1 = (const float*)d_in[10];
    const float* Wq_r = (const float*)d_in[11]; const float* bq_r = (const float*)d_in[12];
    const float* Wk_r = (const float*)d_in[13]; const float* bk_r = (const float*)d_in[14];
    const float* Wv_r = (const float*)d_in[15]; const float* bv_r = (const float*)d_in[16];
    const float* Ws_r = (const float*)d_in[17]; const float* bs_r = (const float*)d_in[18];
    const float* fc1w = (const float*)d_in[19]; const float* fc1b = (const float*)d_in[20];
    const float* fc2w = (const float*)d_in[21]; const float* fc2b = (const float*)d_in[22];
    const float* arcw = (const float*)d_in[23];
    float* out = (float*)d_out;

    const int* esrc = ei;
    const int* edst = ei + N_EDGES;

    char* base = (char*)d_ws;
    size_t off = 0;
    auto alloc = [&](size_t bytes) -> void* {
        off = (off + 255) & ~(size_t)255;
        void* p = base + off;
        off += bytes;
        return p;
    };
    float*    qs  = (float*)alloc((size_t)N_NODES * LDQS * 4);      // ~53.8 MB
    ushort_t* kv  = (ushort_t*)alloc((size_t)N_NODES * LDKV * 2);   // ~46.1 MB
    ushort_t* xb  = (ushort_t*)alloc((size_t)N_NODES * DIM_IN * 2);
    ushort_t* hb0 = (ushort_t*)alloc((size_t)N_NODES * HIDDEN * 2);
    ushort_t* hb1 = (ushort_t*)alloc((size_t)N_NODES * HIDDEN * 2);
    float*    hf  = (float*)alloc((size_t)N_NODES * HIDDEN * 4);
    ushort_t* Wb0 = (ushort_t*)alloc((size_t)DIM_IN * NALL * 2);
    ushort_t* Wbr = (ushort_t*)alloc((size_t)4 * HIDDEN * NALL * 2);
    int*   deg     = (int*)alloc(N_NODES * 4);
    int*   row_ptr = (int*)alloc((N_NODES + 1) * 4);
    int*   cursor  = (int*)alloc(N_NODES * 4);
    int*   csrc    = (int*)alloc(N_EDGES * 4);
    float* gsum    = (float*)alloc(NGRAPH * HIDDEN * 4);
    int*   gcnt    = (int*)alloc(NGRAPH * 4);

    // bf16 conversions
    k_cvt<<<(N_NODES * DIM_IN + 255) / 256, 256, 0, stream>>>(x, xb, N_NODES * DIM_IN);
    k_cvt_w<<<(DIM_IN * NALL + 255) / 256, 256, 0, stream>>>(Wq1, Wk1, Wv1, Ws1, DIM_IN, Wb0);
    for (int i = 0; i < 4; i++) {
        k_cvt_w<<<(HIDDEN * NALL + 255) / 256, 256, 0, stream>>>(
            Wq_r + (size_t)i * HIDDEN * HD, Wk_r + (size_t)i * HIDDEN * HD,
            Wv_r + (size_t)i * HIDDEN * HD, Ws_r + (size_t)i * HIDDEN * HIDDEN,
            HIDDEN, Wbr + (size_t)i * HIDDEN * NALL);
    }

    // CSR by destination
    hipMemsetAsync(deg, 0, N_NODES * 4, stream);
    k_deg<<<(N_EDGES + 255) / 256, 256, 0, stream>>>(edst, deg);
    k_scan<<<1, 1024, 0, stream>>>(deg, row_ptr, cursor);
    k_scatter<<<(N_EDGES + 255) / 256, 256, 0, stream>>>(esrc, edst, cursor, csrc);

    const ushort_t* Ain = xb;
    ushort_t* hbcur = hb0;
    for (int L = 0; L < 5; L++) {
        const ushort_t* Wb = (L == 0) ? Wb0 : (Wbr + (size_t)(L - 1) * HIDDEN * NALL);
        const float *bq, *bk, *bv, *bs;
        if (L == 0) { bq = bq1; bk = bk1; bv = bv1; bs = bs1; }
        else {
            int i = L - 1;
            bq = bq_r + (size_t)i * HD; bk = bk_r + (size_t)i * HD;
            bv = bv_r + (size_t)i * HD; bs = bs_r + (size_t)i * HIDDEN;
        }
        dim3 g(19, (N_NODES + 127) / 128);
        if (L == 0)
            gemm_qkvs_mfma<DIM_IN><<<g, 256, 0, stream>>>(Ain, N_NODES, Wb,
                                                          bq, bk, bv, bs, qs, kv);
        else
            gemm_qkvs_mfma<HIDDEN><<<g, 256, 0, stream>>>(Ain, N_NODES, Wb,
                                                          bq, bk, bv, bs, qs, kv);
        node_attn<<<N_NODES, 192, 0, stream>>>(qs, kv, row_ptr, csrc, hbcur, hf);
        Ain = hbcur;
        hbcur = (hbcur == hb0) ? hb1 : hb0;
    }

    hipMemsetAsync(gsum, 0, NGRAPH * HIDDEN * 4, stream);
    hipMemsetAsync(gcnt, 0, NGRAPH * 4, stream);
    k_pool<<<((N_NODES * HIDDEN) + 255) / 256, 256, 0, stream>>>(hf, batch, gsum, gcnt);
    k_head<<<NGRAPH, 128, 0, stream>>>(gsum, gcnt, fc1w, fc1b, fc2w, fc2b, arcw, out);
}

// Round 6
// 775.992 us; speedup vs baseline: 2.6886x; 1.2386x over previous
//
#include <hip/hip_runtime.h>
#include <math.h>

#define N_NODES 20000
#define N_EDGES 160000
#define DIM_IN  128
#define HIDDEN  96
#define NH      6
#define HD      576      // NH*HIDDEN
#define LDROW   1824     // bf16 row: Q(576) | K(576) | V(576) | S(96)
#define NALL    1824     // concat QKVS output cols
#define NGRAPH  512
#define NCLS    128
#define CHUNK   32       // edges per softmax chunk
#define SLD     104      // LDS stage row stride (ushorts)

typedef unsigned short ushort_t;
typedef __attribute__((ext_vector_type(8))) short bf16x8;
typedef __attribute__((ext_vector_type(4))) float f32x4;

static __device__ __forceinline__ ushort_t f2bf(float f) {
    unsigned int u = __float_as_uint(f);
    return (ushort_t)((u + 0x7fffu + ((u >> 16) & 1u)) >> 16);  // RNE
}
static __device__ __forceinline__ float bfs(ushort_t u) { return __uint_as_float((unsigned int)u << 16); }
static __device__ __forceinline__ float bflo(unsigned int u) { return __uint_as_float(u << 16); }
static __device__ __forceinline__ float bfhi(unsigned int u) { return __uint_as_float(u & 0xffff0000u); }

// ---------------------------------------------------------------------------
__global__ void k_cvt(const float* __restrict__ src, ushort_t* __restrict__ dst, int n)
{
    int i = blockIdx.x * blockDim.x + threadIdx.x;
    if (i < n) dst[i] = f2bf(src[i]);
}

// Build concatenated bf16 weight matrix [K x 1824] = [Wq | Wk | Wv | Ws]
__global__ void k_cvt_w(const float* __restrict__ Wq, const float* __restrict__ Wk,
                        const float* __restrict__ Wv, const float* __restrict__ Ws,
                        int K, ushort_t* __restrict__ dst)
{
    int i = blockIdx.x * blockDim.x + threadIdx.x;
    if (i >= K * NALL) return;
    int k = i / NALL, n = i - k * NALL;
    float v;
    if (n < 576)       v = Wq[(size_t)k * HD + n];
    else if (n < 1152) v = Wk[(size_t)k * HD + (n - 576)];
    else if (n < 1728) v = Wv[(size_t)k * HD + (n - 1152)];
    else               v = Ws[(size_t)k * HIDDEN + (n - 1728)];
    dst[i] = f2bf(v);
}

// ---------------------------------------------------------------------------
// bf16 MFMA fused QKVS projection. Block 128(M) x 96(N), 4 waves (2x2), each
// 64x48 via 4x3 mfma_f32_16x16x32_bf16. Epilogue: bias + bf16 LDS stage
// (aliasing As) + cooperative uint4 stores (192B segments).
// grid.x = 19 col-blocks of 96 -> one bf16 output row kvqs[1824] = Q|K|V|S.
// ---------------------------------------------------------------------------
template<int KDIM>
__global__ __launch_bounds__(256) void gemm_qkvs_mfma(
    const ushort_t* __restrict__ A, int M,
    const ushort_t* __restrict__ Wb,
    const float* __restrict__ bq, const float* __restrict__ bk,
    const float* __restrict__ bv, const float* __restrict__ bs,
    ushort_t* __restrict__ kvqs)
{
    constexpr int LDA = KDIM + 8;
    constexpr int K8  = KDIM >> 3;
    __shared__ __align__(16) ushort_t As[128 * LDA];   // >= 128*SLD for stage
    __shared__ __align__(16) ushort_t Bs[96 * LDA];
    const int t    = threadIdx.x;
    const int lane = t & 63;
    const int w    = t >> 6;
    const int wm   = w & 1, wn = w >> 1;
    const int quad = lane >> 4;
    const int l16  = lane & 15;
    const int m0   = blockIdx.y * 128;
    const int rb   = blockIdx.x;          // 0..18
    const int n0   = rb * 96;

    // stage A tile [128 x K] bf16
    for (int idx = t; idx < 128 * K8; idx += 256) {
        int r = idx / K8, kc = idx - r * K8;
        int row = m0 + r;
        uint4 v = make_uint4(0u, 0u, 0u, 0u);
        if (row < M) v = *(const uint4*)(A + (size_t)row * KDIM + kc * 8);
        *(uint4*)(&As[r * LDA + kc * 8]) = v;
    }
    // stage B transposed: Bs[c][k] = Wb[k][n0+c]
    for (int idx = t; idx < 24 * KDIM; idx += 256) {
        int k = idx / 24, c4 = idx - k * 24;
        ushort4 v = *(const ushort4*)(Wb + (size_t)k * NALL + n0 + c4 * 4);
        Bs[(c4 * 4 + 0) * LDA + k] = v.x;
        Bs[(c4 * 4 + 1) * LDA + k] = v.y;
        Bs[(c4 * 4 + 2) * LDA + k] = v.z;
        Bs[(c4 * 4 + 3) * LDA + k] = v.w;
    }
    __syncthreads();

    f32x4 acc[4][3] = {};
    #pragma unroll
    for (int ks = 0; ks < KDIM; ks += 32) {
        bf16x8 af[4], bfv[3];
        #pragma unroll
        for (int i = 0; i < 4; i++)
            af[i] = *(const bf16x8*)(&As[(wm * 64 + i * 16 + l16) * LDA + ks + quad * 8]);
        #pragma unroll
        for (int j = 0; j < 3; j++)
            bfv[j] = *(const bf16x8*)(&Bs[(wn * 48 + j * 16 + l16) * LDA + ks + quad * 8]);
        #pragma unroll
        for (int i = 0; i < 4; i++)
            #pragma unroll
            for (int j = 0; j < 3; j++)
                acc[i][j] = __builtin_amdgcn_mfma_f32_16x16x32_bf16(af[i], bfv[j], acc[i][j], 0, 0, 0);
    }

    // bias select (region boundaries are multiples of 96)
    const float* biasp;
    int cb0;
    if (rb < 6)       { biasp = bq; cb0 = n0; }
    else if (rb < 12) { biasp = bk; cb0 = n0 - 576; }
    else if (rb < 18) { biasp = bv; cb0 = n0 - 1152; }
    else              { biasp = bs; cb0 = 0; }
    float bj[3];
    #pragma unroll
    for (int j = 0; j < 3; j++) bj[j] = biasp[cb0 + wn * 48 + j * 16 + l16];

    // stage results bf16 into As (aliased; stride SLD=104 <= LDA+... safe: 128*104 <= 128*LDA)
    __syncthreads();
    ushort_t* stage = As;
    #pragma unroll
    for (int i = 0; i < 4; i++) {
        #pragma unroll
        for (int r = 0; r < 4; r++) {
            int row = wm * 64 + i * 16 + quad * 4 + r;
            #pragma unroll
            for (int j = 0; j < 3; j++)
                stage[row * SLD + wn * 48 + j * 16 + l16] = f2bf(acc[i][j][r] + bj[j]);
        }
    }
    __syncthreads();

    // cooperative coalesced store: 128 rows x 12 uint4
    for (int idx = t; idx < 128 * 12; idx += 256) {
        int r = idx / 12, v = idx - r * 12;
        int row = m0 + r;
        if (row < M)
            *(uint4*)(kvqs + (size_t)row * LDROW + n0 + v * 8) =
                *(const uint4*)(&stage[r * SLD + v * 8]);
    }
}

// ---------------------------------------------------------------------------
// CSR construction by destination node
// ---------------------------------------------------------------------------
__global__ void k_deg(const int* __restrict__ edst, int* __restrict__ deg)
{
    int e = blockIdx.x * blockDim.x + threadIdx.x;
    if (e < N_EDGES) atomicAdd(&deg[edst[e]], 1);
}

__global__ __launch_bounds__(1024) void k_scan(const int* __restrict__ deg,
                                               int* __restrict__ row_ptr,
                                               int* __restrict__ cursor)
{
    __shared__ int part[1024];
    int t = threadIdx.x;
    const int chunk = (N_NODES + 1023) / 1024;  // 20
    int b = t * chunk;
    int s = 0;
    for (int i = 0; i < chunk; i++)
        if (b + i < N_NODES) s += deg[b + i];
    part[t] = s;
    __syncthreads();
    for (int o = 1; o < 1024; o <<= 1) {
        int v = (t >= o) ? part[t - o] : 0;
        __syncthreads();
        part[t] += v;
        __syncthreads();
    }
    int run = part[t] - s;
    for (int i = 0; i < chunk; i++) {
        if (b + i < N_NODES) {
            row_ptr[b + i] = run;
            cursor[b + i]  = run;
            run += deg[b + i];
        }
    }
    if (t == 1023) row_ptr[N_NODES] = part[1023];
}

__global__ void k_scatter(const int* __restrict__ esrc, const int* __restrict__ edst,
                          int* __restrict__ cursor, int* __restrict__ csrc)
{
    int e = blockIdx.x * blockDim.x + threadIdx.x;
    if (e < N_EDGES) {
        int pos = atomicAdd(&cursor[edst[e]], 1);
        csrc[pos] = esrc[e];
    }
}

// ---------------------------------------------------------------------------
// Fused per-destination-node attention.
// pass 1: quarter-split — 4 lanes per edge, each a 24-elem partial dot
//         (3 uint4 loads) + 2 shfl_xor; 8 edges in flight per lane-group.
// pass 2: dim-parallel V aggregation, unroll-4 staged register loads.
// ---------------------------------------------------------------------------
__global__ __launch_bounds__(192) void node_attn(
    const ushort_t* __restrict__ kvqs,
    const int* __restrict__ row_ptr, const int* __restrict__ csrc,
    ushort_t* __restrict__ hb, float* __restrict__ hf)
{
    const int n = blockIdx.x;
    const int t = threadIdx.x;
    const int lane = t & 31;
    const int g = t >> 5;              // head group 0..5
    const int el = lane >> 2;          // edge slot 0..7
    const int qr = lane & 3;           // quarter 0..3

    __shared__ float Qs[HD];
    __shared__ float wbuf[CHUNK * NH];
    __shared__ int   srcs[CHUNK];
    __shared__ float m[NH], l[NH], scale[NH], linv[NH];
    __shared__ float arr[HD];

    const int beg = row_ptr[n], end = row_ptr[n + 1];
    const ushort_t* qk = kvqs + (size_t)n * LDROW;
    Qs[t] = bfs(qk[t]); Qs[t + 192] = bfs(qk[t + 192]); Qs[t + 384] = bfs(qk[t + 384]);
    if (t < NH) { m[t] = -1e30f; l[t] = 0.f; }

    const int d0 = t, d1 = t + 192, d2 = t + 384;
    const int h0 = d0 / HIDDEN, h1 = d1 / HIDDEN, h2 = d2 / HIDDEN;
    float a0 = 0.f, a1 = 0.f, a2 = 0.f;
    const float qa = 0.10206207261596577f; // 1/sqrt(96)

    for (int cb = beg; cb < end; cb += CHUNK) {
        const int c = min(CHUNK, end - cb);
        __syncthreads();
        if (t < c) srcs[t] = csrc[cb + t];
        __syncthreads();

        // ---- pass 1: logits, 4 lanes per edge ---------------------------
        for (int eb = 0; eb < c; eb += 8) {
            int e8 = eb + el;
            bool act = e8 < c;
            int src = srcs[act ? e8 : 0];
            const uint4* kp = (const uint4*)(kvqs + (size_t)src * LDROW + HD + g * HIDDEN + qr * 24);
            uint4 r0 = kp[0], r1 = kp[1], r2 = kp[2];
            const float* qb = &Qs[g * HIDDEN + qr * 24];
            float p = 0.f;
            unsigned int uu[12] = {r0.x, r0.y, r0.z, r0.w, r1.x, r1.y, r1.z, r1.w,
                                   r2.x, r2.y, r2.z, r2.w};
            #pragma unroll
            for (int k2 = 0; k2 < 12; k2++)
                p += bflo(uu[k2]) * qb[2 * k2] + bfhi(uu[k2]) * qb[2 * k2 + 1];
            p += __shfl_xor(p, 1, 32);
            p += __shfl_xor(p, 2, 32);
            if (act && qr == 0) wbuf[e8 * NH + g] = p * qa;
        }
        __syncthreads();

        // ---- softmax bookkeeping ---------------------------------------
        if (t < NH) {
            float cm = m[t];
            for (int e = 0; e < c; e++) cm = fmaxf(cm, wbuf[e * NH + t]);
            scale[t] = __expf(m[t] - cm);
            m[t] = cm;
            l[t] *= scale[t];
        }
        __syncthreads();

        a0 *= scale[h0]; a1 *= scale[h1]; a2 *= scale[h2];
        float lp = 0.f;
        for (int e = lane; e < c; e += 32) {
            float w2 = __expf(wbuf[e * NH + g] - m[g]);
            wbuf[e * NH + g] = w2;
            lp += w2;
        }
        #pragma unroll
        for (int o = 16; o; o >>= 1) lp += __shfl_xor(lp, o, 32);
        if (lane == 0) l[g] += lp;
        __syncthreads();

        // ---- pass 2: V aggregation, unroll-4 staged loads ---------------
        int e = 0;
        for (; e + 4 <= c; e += 4) {
            ushort_t r0[4], r1[4], r2[4];
            #pragma unroll
            for (int j = 0; j < 4; j++) {
                const ushort_t* v = kvqs + (size_t)srcs[e + j] * LDROW + 2 * HD;
                r0[j] = v[d0]; r1[j] = v[d1]; r2[j] = v[d2];
            }
            #pragma unroll
            for (int j = 0; j < 4; j++) {
                const float* w2 = wbuf + (e + j) * NH;
                a0 += w2[h0] * bfs(r0[j]);
                a1 += w2[h1] * bfs(r1[j]);
                a2 += w2[h2] * bfs(r2[j]);
            }
        }
        for (; e < c; e++) {
            const ushort_t* v = kvqs + (size_t)srcs[e] * LDROW + 2 * HD;
            const float* w2 = wbuf + e * NH;
            a0 += w2[h0] * bfs(v[d0]);
            a1 += w2[h1] * bfs(v[d1]);
            a2 += w2[h2] * bfs(v[d2]);
        }
    }

    if (t < NH) linv[t] = (l[t] > 0.f) ? 1.0f / l[t] : 0.f;
    __syncthreads();
    arr[d0] = a0 * linv[h0]; arr[d1] = a1 * linv[h1]; arr[d2] = a2 * linv[h2];
    __syncthreads();

    if (t < HIDDEN) {
        float s = (arr[t] + arr[HIDDEN + t] + arr[2 * HIDDEN + t] +
                   arr[3 * HIDDEN + t] + arr[4 * HIDDEN + t] + arr[5 * HIDDEN + t])
                  * (1.0f / 6.0f);
        s += bfs(qk[3 * HD + t]);   // skip connection S (bf16)
        s = fmaxf(s, 0.0f);
        hb[n * HIDDEN + t] = f2bf(s);
        hf[n * HIDDEN + t] = s;
    }
}

// ---------------------------------------------------------------------------
__global__ void k_pool(const float* __restrict__ h, const int* __restrict__ batch,
                       float* __restrict__ gsum, int* __restrict__ gcnt)
{
    int i = blockIdx.x * blockDim.x + threadIdx.x;
    if (i >= N_NODES * HIDDEN) return;
    int n = i / HIDDEN, d = i - n * HIDDEN;
    int b = batch[n];
    atomicAdd(&gsum[b * HIDDEN + d], h[i]);
    if (d == 0) atomicAdd(&gcnt[b], 1);
}

__global__ __launch_bounds__(128) void k_head(
    const float* __restrict__ gsum, const int* __restrict__ gcnt,
    const float* __restrict__ fc1w, const float* __restrict__ fc1b,
    const float* __restrict__ fc2w, const float* __restrict__ fc2b,
    const float* __restrict__ arcw, float* __restrict__ out)
{
    int g = blockIdx.x, t = threadIdx.x;
    __shared__ float v0[HIDDEN], v1[HIDDEN], v2[HIDDEN];
    __shared__ float gnorm;
    float cnt = fmaxf((float)gcnt[g], 1.0f);
    if (t < HIDDEN) v0[t] = gsum[g * HIDDEN + t] / cnt;
    __syncthreads();
    if (t < HIDDEN) {
        float s = fc1b[t];
        for (int k = 0; k < HIDDEN; k++) s += v0[k] * fc1w[k * HIDDEN + t];
        v1[t] = fmaxf(s, 0.f);
    }
    __syncthreads();
    if (t < HIDDEN) {
        float s = fc2b[t];
        for (int k = 0; k < HIDDEN; k++) s += v1[k] * fc2w[k * HIDDEN + t];
        v2[t] = fmaxf(s, 0.f);
    }
    __syncthreads();
    if (t == 0) {
        float s = 0.f;
        for (int k = 0; k < HIDDEN; k++) s += v2[k] * v2[k];
        gnorm = sqrtf(s) + 1e-12f;
    }
    __syncthreads();
    if (t < NCLS) {
        float dot = 0.f, wn = 0.f;
        const float* wr = arcw + (size_t)t * HIDDEN;
        for (int k = 0; k < HIDDEN; k++) {
            float w = wr[k];
            dot += w * v2[k];
            wn  += w * w;
        }
        out[g * NCLS + t] = 30.0f * dot / (gnorm * (sqrtf(wn) + 1e-12f));
    }
}

// ---------------------------------------------------------------------------
extern "C" void kernel_launch(void* const* d_in, const int* in_sizes, int n_in,
                              void* d_out, int out_size, void* d_ws, size_t ws_size,
                              hipStream_t stream)
{
    (void)in_sizes; (void)n_in; (void)out_size; (void)ws_size;

    const float* x     = (const float*)d_in[0];
    const int*   ei    = (const int*)d_in[1];
    const int*   batch = (const int*)d_in[2];
    const float* Wq1 = (const float*)d_in[3];  const float* bq1 = (const float*)d_in[4];
    const float* Wk1 = (const float*)d_in[5];  const float* bk1 = (const float*)d_in[6];
    const float* Wv1 = (const float*)d_in[7];  const float* bv1 = (const float*)d_in[8];
    const float* Ws1 = (const float*)d_in[9];  const float* bs1 = (const float*)d_in[10];
    const float* Wq_r = (const float*)d_in[11]; const float* bq_r = (const float*)d_in[12];
    const float* Wk_r = (const float*)d_in[13]; const float* bk_r = (const float*)d_in[14];
    const float* Wv_r = (const float*)d_in[15]; const float* bv_r = (const float*)d_in[16];
    const float* Ws_r = (const float*)d_in[17]; const float* bs_r = (const float*)d_in[18];
    const float* fc1w = (const float*)d_in[19]; const float* fc1b = (const float*)d_in[20];
    const float* fc2w = (const float*)d_in[21]; const float* fc2b = (const float*)d_in[22];
    const float* arcw = (const float*)d_in[23];
    float* out = (float*)d_out;

    const int* esrc = ei;
    const int* edst = ei + N_EDGES;

    char* base = (char*)d_ws;
    size_t off = 0;
    auto alloc = [&](size_t bytes) -> void* {
        off = (off + 255) & ~(size_t)255;
        void* p = base + off;
        off += bytes;
        return p;
    };
    ushort_t* kvqs = (ushort_t*)alloc((size_t)N_NODES * LDROW * 2);  // ~73 MB
    ushort_t* xb  = (ushort_t*)alloc((size_t)N_NODES * DIM_IN * 2);
    ushort_t* hb0 = (ushort_t*)alloc((size_t)N_NODES * HIDDEN * 2);
    ushort_t* hb1 = (ushort_t*)alloc((size_t)N_NODES * HIDDEN * 2);
    float*    hf  = (float*)alloc((size_t)N_NODES * HIDDEN * 4);
    ushort_t* Wb0 = (ushort_t*)alloc((size_t)DIM_IN * NALL * 2);
    ushort_t* Wbr = (ushort_t*)alloc((size_t)4 * HIDDEN * NALL * 2);
    int*   deg     = (int*)alloc(N_NODES * 4);
    int*   row_ptr = (int*)alloc((N_NODES + 1) * 4);
    int*   cursor  = (int*)alloc(N_NODES * 4);
    int*   csrc    = (int*)alloc(N_EDGES * 4);
    float* gsum    = (float*)alloc(NGRAPH * HIDDEN * 4);
    int*   gcnt    = (int*)alloc(NGRAPH * 4);

    // bf16 conversions
    k_cvt<<<(N_NODES * DIM_IN + 255) / 256, 256, 0, stream>>>(x, xb, N_NODES * DIM_IN);
    k_cvt_w<<<(DIM_IN * NALL + 255) / 256, 256, 0, stream>>>(Wq1, Wk1, Wv1, Ws1, DIM_IN, Wb0);
    for (int i = 0; i < 4; i++) {
        k_cvt_w<<<(HIDDEN * NALL + 255) / 256, 256, 0, stream>>>(
            Wq_r + (size_t)i * HIDDEN * HD, Wk_r + (size_t)i * HIDDEN * HD,
            Wv_r + (size_t)i * HIDDEN * HD, Ws_r + (size_t)i * HIDDEN * HIDDEN,
            HIDDEN, Wbr + (size_t)i * HIDDEN * NALL);
    }

    // CSR by destination
    hipMemsetAsync(deg, 0, N_NODES * 4, stream);
    k_deg<<<(N_EDGES + 255) / 256, 256, 0, stream>>>(edst, deg);
    k_scan<<<1, 1024, 0, stream>>>(deg, row_ptr, cursor);
    k_scatter<<<(N_EDGES + 255) / 256, 256, 0, stream>>>(esrc, edst, cursor, csrc);

    const ushort_t* Ain = xb;
    ushort_t* hbcur = hb0;
    for (int L = 0; L < 5; L++) {
        const ushort_t* Wb = (L == 0) ? Wb0 : (Wbr + (size_t)(L - 1) * HIDDEN * NALL);
        const float *bq, *bk, *bv, *bs;
        if (L == 0) { bq = bq1; bk = bk1; bv = bv1; bs = bs1; }
        else {
            int i = L - 1;
            bq = bq_r + (size_t)i * HD; bk = bk_r + (size_t)i * HD;
            bv = bv_r + (size_t)i * HD; bs = bs_r + (size_t)i * HIDDEN;
        }
        dim3 g(19, (N_NODES + 127) / 128);
        if (L == 0)
            gemm_qkvs_mfma<DIM_IN><<<g, 256, 0, stream>>>(Ain, N_NODES, Wb,
                                                          bq, bk, bv, bs, kvqs);
        else
            gemm_qkvs_mfma<HIDDEN><<<g, 256, 0, stream>>>(Ain, N_NODES, Wb,
                                                          bq, bk, bv, bs, kvqs);
        node_attn<<<N_NODES, 192, 0, stream>>>(kvqs, row_ptr, csrc, hbcur, hf);
        Ain = hbcur;
        hbcur = (hbcur == hb0) ? hb1 : hb0;
    }

    hipMemsetAsync(gsum, 0, NGRAPH * HIDDEN * 4, stream);
    hipMemsetAsync(gcnt, 0, NGRAPH * 4, stream);
    k_pool<<<((N_NODES * HIDDEN) + 255) / 256, 256, 0, stream>>>(hf, batch, gsum, gcnt);
    k_head<<<NGRAPH, 128, 0, stream>>>(gsum, gcnt, fc1w, fc1b, fc2w, fc2b, arcw, out);
}